// Round 1
// baseline (16429.344 us; speedup 1.0000x reference)
//
#include <hip/hip_runtime.h>

// Problem constants (match reference)
constexpr int U_N = 100000;   // users
constexpr int I_N = 100000;   // items
constexpr int D   = 64;       // latent dim
constexpr int NL  = 3;        // layers
constexpr int NN  = U_N + I_N;          // 200000 nodes
constexpr long long ND4 = (long long)NN * D / 4;   // float4 elements per buffer
constexpr long long UD4 = (long long)U_N * D / 4;

__device__ __forceinline__ float sigmoidf_(float x) {
    return 1.0f / (1.0f + expf(-x));
}

// Layer-0 fusion: bufA = fused emb, acc = bufA, bufB = 0
__global__ void fuse0_kernel(const float* __restrict__ user_emb,
                             const float* __restrict__ item_emb,
                             const float* __restrict__ symptom_emb,
                             const float* __restrict__ herb_emb,
                             const float* __restrict__ user_lw,
                             const float* __restrict__ item_lw,
                             float* __restrict__ bufA,
                             float* __restrict__ bufB,
                             float* __restrict__ acc) {
    long long idx = (long long)blockIdx.x * blockDim.x + threadIdx.x;
    if (idx >= ND4) return;
    float a0 = sigmoidf_(user_lw[0]);
    float b0 = sigmoidf_(item_lw[0]);
    float4 e, s;
    float w;
    if (idx < UD4) {
        e = ((const float4*)user_emb)[idx];
        s = ((const float4*)symptom_emb)[idx];
        w = a0;
    } else {
        long long j = idx - UD4;
        e = ((const float4*)item_emb)[j];
        s = ((const float4*)herb_emb)[j];
        w = b0;
    }
    float4 r;
    r.x = w * e.x + (1.0f - w) * s.x;
    r.y = w * e.y + (1.0f - w) * s.y;
    r.z = w * e.z + (1.0f - w) * s.z;
    r.w = w * e.w + (1.0f - w) * s.w;
    ((float4*)bufA)[idx] = r;
    ((float4*)acc)[idx]  = r;
    float4 z; z.x = z.y = z.z = z.w = 0.0f;
    ((float4*)bufB)[idx] = z;
}

// SpMM scatter: dst[row] += val * src[col], one thread per (edge, dim-quad)
__global__ void spmm_scatter_kernel(const float* __restrict__ edge_val,
                                    const int*   __restrict__ edge_row,
                                    const int*   __restrict__ edge_col,
                                    const float* __restrict__ src,
                                    float*       __restrict__ dst,
                                    long long total) {
    long long idx = (long long)blockIdx.x * blockDim.x + threadIdx.x;
    if (idx >= total) return;
    long long e = idx >> 4;       // edge index
    int       q = (int)(idx & 15); // which float4 of the 64-dim row
    int r = edge_row[e];
    int c = edge_col[e];
    float v = edge_val[e];
    float4 x = *(const float4*)(src + (long long)c * D + q * 4);
    float* d = dst + (long long)r * D + q * 4;
    atomicAdd(d + 0, v * x.x);
    atomicAdd(d + 1, v * x.y);
    atomicAdd(d + 2, v * x.z);
    atomicAdd(d + 3, v * x.w);
}

// Per-layer fusion: bufA = w*bufB + (1-w)*sem ; acc += bufA ; bufB = 0
__global__ void fuse_layer_kernel(const float* __restrict__ symptom_emb,
                                  const float* __restrict__ herb_emb,
                                  const float* __restrict__ user_lw,
                                  const float* __restrict__ item_lw,
                                  int layer,
                                  float* __restrict__ bufA,
                                  float* __restrict__ bufB,
                                  float* __restrict__ acc) {
    long long idx = (long long)blockIdx.x * blockDim.x + threadIdx.x;
    if (idx >= ND4) return;
    float a = sigmoidf_(user_lw[layer]);
    float b = sigmoidf_(item_lw[layer]);
    float4 m = ((float4*)bufB)[idx];
    float4 z; z.x = z.y = z.z = z.w = 0.0f;
    ((float4*)bufB)[idx] = z;   // re-zero for next layer's scatter
    float4 s;
    float w;
    if (idx < UD4) {
        s = ((const float4*)symptom_emb)[idx];
        w = a;
    } else {
        s = ((const float4*)herb_emb)[idx - UD4];
        w = b;
    }
    float4 r;
    r.x = w * m.x + (1.0f - w) * s.x;
    r.y = w * m.y + (1.0f - w) * s.y;
    r.z = w * m.z + (1.0f - w) * s.z;
    r.w = w * m.w + (1.0f - w) * s.w;
    ((float4*)bufA)[idx] = r;
    float4 ac = ((float4*)acc)[idx];
    ac.x += r.x; ac.y += r.y; ac.z += r.z; ac.w += r.w;
    ((float4*)acc)[idx] = ac;
}

// Readout: one wave per (user,item) pair; gamma = dot(acc_u, acc_i) / 16
__global__ void gamma_kernel(const float* __restrict__ acc,
                             const int* __restrict__ users,
                             const int* __restrict__ items,
                             float* __restrict__ out,
                             int B) {
    int gtid = blockIdx.x * blockDim.x + threadIdx.x;
    int wid  = gtid >> 6;        // pair index (one 64-lane wave per pair)
    int lane = threadIdx.x & 63;
    if (wid >= B) return;
    int u  = users[wid];
    int it = items[wid];
    float su = acc[(long long)u * D + lane];
    float si = acc[((long long)(U_N + it)) * D + lane];
    float p = su * si;
    #pragma unroll
    for (int off = 32; off > 0; off >>= 1)
        p += __shfl_down(p, off, 64);
    if (lane == 0) out[wid] = p * (1.0f / 16.0f);
}

extern "C" void kernel_launch(void* const* d_in, const int* in_sizes, int n_in,
                              void* d_out, int out_size, void* d_ws, size_t ws_size,
                              hipStream_t stream) {
    const float* user_emb    = (const float*)d_in[0];
    const float* item_emb    = (const float*)d_in[1];
    const float* symptom_emb = (const float*)d_in[2];
    const float* herb_emb    = (const float*)d_in[3];
    const float* user_lw     = (const float*)d_in[4];
    const float* item_lw     = (const float*)d_in[5];
    const float* edge_val    = (const float*)d_in[6];
    const int*   edge_row    = (const int*)d_in[7];
    const int*   edge_col    = (const int*)d_in[8];
    const int*   users       = (const int*)d_in[9];
    const int*   items       = (const int*)d_in[10];
    float* out = (float*)d_out;

    const long long E = in_sizes[6];
    const int B = in_sizes[9];

    // Workspace layout: 3 buffers of N*D floats (51.2 MB each)
    float* bufA = (float*)d_ws;                       // current layer emb
    float* bufB = bufA + (long long)NN * D;           // scatter target
    float* acc  = bufB + (long long)NN * D;           // running sum over layers

    const int TPB = 256;

    // Layer 0 fusion + buffer init
    {
        long long total = ND4;
        int blocks = (int)((total + TPB - 1) / TPB);
        fuse0_kernel<<<blocks, TPB, 0, stream>>>(user_emb, item_emb, symptom_emb,
                                                 herb_emb, user_lw, item_lw,
                                                 bufA, bufB, acc);
    }

    // 3 propagation layers
    for (int layer = 1; layer <= NL; ++layer) {
        long long total = E * 16;  // (edge, dim-quad) threads
        int blocks = (int)((total + TPB - 1) / TPB);
        spmm_scatter_kernel<<<blocks, TPB, 0, stream>>>(edge_val, edge_row, edge_col,
                                                        bufA, bufB, total);
        int fblocks = (int)((ND4 + TPB - 1) / TPB);
        fuse_layer_kernel<<<fblocks, TPB, 0, stream>>>(symptom_emb, herb_emb,
                                                       user_lw, item_lw, layer,
                                                       bufA, bufB, acc);
    }

    // Readout
    {
        int total = B * 64;
        int blocks = (total + TPB - 1) / TPB;
        gamma_kernel<<<blocks, TPB, 0, stream>>>(acc, users, items, out, B);
    }
}

// Round 2
// 1735.049 us; speedup vs baseline: 9.4691x; 9.4691x over previous
//
#include <hip/hip_runtime.h>

// Problem constants (match reference)
constexpr int U_N = 100000;   // users
constexpr int I_N = 100000;   // items
constexpr int D   = 64;       // latent dim
constexpr int NL  = 3;        // layers
constexpr int NN  = U_N + I_N;              // 200000 nodes
constexpr long long NDLL = (long long)NN * D;
constexpr long long ND4  = NDLL / 4;
constexpr long long UD4  = (long long)U_N * D / 4;
constexpr int SCAN_B = 256;
constexpr int NB     = (NN + SCAN_B - 1) / SCAN_B;   // 782 blocks in level-1 scan

__device__ __forceinline__ float sigmoidf_(float x) {
    return 1.0f / (1.0f + expf(-x));
}

// ---------------------------------------------------------------------------
// Layer-0 fusion: buf0 = fused emb, acc = buf0. Optionally zero bufB (fallback
// scatter path needs a zeroed target; fast gather path passes nullptr).
// ---------------------------------------------------------------------------
__global__ void fuse0_kernel(const float* __restrict__ user_emb,
                             const float* __restrict__ item_emb,
                             const float* __restrict__ symptom_emb,
                             const float* __restrict__ herb_emb,
                             const float* __restrict__ user_lw,
                             const float* __restrict__ item_lw,
                             float* __restrict__ buf0,
                             float* __restrict__ acc,
                             float* __restrict__ bufB_or_null) {
    long long idx = (long long)blockIdx.x * blockDim.x + threadIdx.x;
    if (idx >= ND4) return;
    float a0 = sigmoidf_(user_lw[0]);
    float b0 = sigmoidf_(item_lw[0]);
    float4 e, s;
    float w;
    if (idx < UD4) {
        e = ((const float4*)user_emb)[idx];
        s = ((const float4*)symptom_emb)[idx];
        w = a0;
    } else {
        long long j = idx - UD4;
        e = ((const float4*)item_emb)[j];
        s = ((const float4*)herb_emb)[j];
        w = b0;
    }
    float4 r;
    r.x = w * e.x + (1.0f - w) * s.x;
    r.y = w * e.y + (1.0f - w) * s.y;
    r.z = w * e.z + (1.0f - w) * s.z;
    r.w = w * e.w + (1.0f - w) * s.w;
    ((float4*)buf0)[idx] = r;
    ((float4*)acc)[idx]  = r;
    if (bufB_or_null) {
        float4 z; z.x = z.y = z.z = z.w = 0.0f;
        ((float4*)bufB_or_null)[idx] = z;
    }
}

// ---------------------------------------------------------------------------
// CSR build: zero counts -> histogram -> 2-level exclusive scan -> fill
// ---------------------------------------------------------------------------
__global__ void zero_counts_kernel(int* __restrict__ counts) {
    int i = blockIdx.x * blockDim.x + threadIdx.x;
    if (i < NN) counts[i] = 0;
}

__global__ void hist_kernel(const int* __restrict__ edge_row,
                            int* __restrict__ counts, int E) {
    int e = blockIdx.x * blockDim.x + threadIdx.x;
    if (e < E) atomicAdd(&counts[edge_row[e]], 1);
}

// level-1: per-block exclusive scan of counts, emit block sums
__global__ void scan1_kernel(const int* __restrict__ counts,
                             int* __restrict__ partial,
                             int* __restrict__ bsum) {
    __shared__ int sm[SCAN_B];
    int tid = threadIdx.x;
    int i = blockIdx.x * SCAN_B + tid;
    int x = (i < NN) ? counts[i] : 0;
    sm[tid] = x;
    __syncthreads();
    for (int off = 1; off < SCAN_B; off <<= 1) {
        int t = (tid >= off) ? sm[tid - off] : 0;
        __syncthreads();
        sm[tid] += t;
        __syncthreads();
    }
    int incl = sm[tid];
    if (i < NN) partial[i] = incl - x;   // exclusive within block
    if (tid == SCAN_B - 1) bsum[blockIdx.x] = incl;
}

// level-2: single-block exclusive scan of the NB block sums (NB=782 <= 1024)
__global__ void scan2_kernel(const int* __restrict__ bsum,
                             int* __restrict__ bsum_excl) {
    __shared__ int sm[1024];
    int tid = threadIdx.x;
    int x = (tid < NB) ? bsum[tid] : 0;
    sm[tid] = x;
    __syncthreads();
    for (int off = 1; off < 1024; off <<= 1) {
        int t = (tid >= off) ? sm[tid - off] : 0;
        __syncthreads();
        sm[tid] += t;
        __syncthreads();
    }
    if (tid < NB) bsum_excl[tid] = sm[tid] - x;
}

// level-3: combine, produce row_ptr and a cursor copy for the fill
__global__ void scan3_kernel(const int* __restrict__ partial,
                             const int* __restrict__ bsum_excl,
                             int* __restrict__ row_ptr,
                             int* __restrict__ cursor, int E) {
    int i = blockIdx.x * blockDim.x + threadIdx.x;
    if (i < NN) {
        int rp = partial[i] + bsum_excl[i >> 8];   // SCAN_B == 256
        row_ptr[i] = rp;
        cursor[i]  = rp;
    }
    if (i == 0) row_ptr[NN] = E;
}

// counting-sort fill: sorted[pos] = (val_bits, col) grouped by row
__global__ void fill_kernel(const float* __restrict__ edge_val,
                            const int*   __restrict__ edge_row,
                            const int*   __restrict__ edge_col,
                            int* __restrict__ cursor,
                            int2* __restrict__ sorted, int E) {
    int e = blockIdx.x * blockDim.x + threadIdx.x;
    if (e >= E) return;
    int r = edge_row[e];
    int pos = atomicAdd(&cursor[r], 1);
    sorted[pos] = make_int2(__float_as_int(edge_val[e]), edge_col[e]);
}

// ---------------------------------------------------------------------------
// Fused CSR SpMM + semantic mix + acc: one 64-lane wave per row, lane = dim.
//   sum = Sum_e val_e * src[col_e][lane]
//   r   = w*sum + (1-w)*sem[row][lane];  dst[row]=r;  acc[row]+=r
// ---------------------------------------------------------------------------
__global__ void spmm_csr_fused_kernel(const int2* __restrict__ sorted,
                                      const int*  __restrict__ row_ptr,
                                      const float* __restrict__ src,
                                      const float* __restrict__ symptom_emb,
                                      const float* __restrict__ herb_emb,
                                      const float* __restrict__ user_lw,
                                      const float* __restrict__ item_lw,
                                      int layer,
                                      float* __restrict__ dst,
                                      float* __restrict__ acc) {
    int wid  = threadIdx.x >> 6;                    // wave in block
    int lane = threadIdx.x & 63;                    // = dim
    int row  = blockIdx.x * (blockDim.x >> 6) + wid;
    if (row >= NN) return;

    int start = row_ptr[row];
    int end   = row_ptr[row + 1];

    float s0 = 0.f, s1 = 0.f, s2 = 0.f, s3 = 0.f;
    int e = start;
    for (; e + 4 <= end; e += 4) {
        int2 a0 = sorted[e + 0];
        int2 a1 = sorted[e + 1];
        int2 a2 = sorted[e + 2];
        int2 a3 = sorted[e + 3];
        float g0 = src[((size_t)a0.y << 6) | lane];
        float g1 = src[((size_t)a1.y << 6) | lane];
        float g2 = src[((size_t)a2.y << 6) | lane];
        float g3 = src[((size_t)a3.y << 6) | lane];
        s0 += __int_as_float(a0.x) * g0;
        s1 += __int_as_float(a1.x) * g1;
        s2 += __int_as_float(a2.x) * g2;
        s3 += __int_as_float(a3.x) * g3;
    }
    for (; e < end; ++e) {
        int2 a = sorted[e];
        s0 += __int_as_float(a.x) * src[((size_t)a.y << 6) | lane];
    }
    float sum = (s0 + s1) + (s2 + s3);

    float w, sem;
    if (row < U_N) {
        w = sigmoidf_(user_lw[layer]);
        sem = symptom_emb[((size_t)row << 6) | lane];
    } else {
        w = sigmoidf_(item_lw[layer]);
        sem = herb_emb[((size_t)(row - U_N) << 6) | lane];
    }
    float r = w * sum + (1.0f - w) * sem;
    size_t o = ((size_t)row << 6) | lane;
    dst[o] = r;
    acc[o] += r;
}

// ---------------------------------------------------------------------------
// Fallback scatter path (round-1 code) in case ws_size is too small for CSR
// ---------------------------------------------------------------------------
__global__ void spmm_scatter_kernel(const float* __restrict__ edge_val,
                                    const int*   __restrict__ edge_row,
                                    const int*   __restrict__ edge_col,
                                    const float* __restrict__ src,
                                    float*       __restrict__ dst,
                                    long long total) {
    long long idx = (long long)blockIdx.x * blockDim.x + threadIdx.x;
    if (idx >= total) return;
    long long e = idx >> 4;
    int       q = (int)(idx & 15);
    int r = edge_row[e];
    int c = edge_col[e];
    float v = edge_val[e];
    float4 x = *(const float4*)(src + (long long)c * D + q * 4);
    float* d = dst + (long long)r * D + q * 4;
    atomicAdd(d + 0, v * x.x);
    atomicAdd(d + 1, v * x.y);
    atomicAdd(d + 2, v * x.z);
    atomicAdd(d + 3, v * x.w);
}

__global__ void fuse_layer_kernel(const float* __restrict__ symptom_emb,
                                  const float* __restrict__ herb_emb,
                                  const float* __restrict__ user_lw,
                                  const float* __restrict__ item_lw,
                                  int layer,
                                  float* __restrict__ bufA,
                                  float* __restrict__ bufB,
                                  float* __restrict__ acc) {
    long long idx = (long long)blockIdx.x * blockDim.x + threadIdx.x;
    if (idx >= ND4) return;
    float a = sigmoidf_(user_lw[layer]);
    float b = sigmoidf_(item_lw[layer]);
    float4 m = ((float4*)bufB)[idx];
    float4 z; z.x = z.y = z.z = z.w = 0.0f;
    ((float4*)bufB)[idx] = z;
    float4 s;
    float w;
    if (idx < UD4) {
        s = ((const float4*)symptom_emb)[idx];
        w = a;
    } else {
        s = ((const float4*)herb_emb)[idx - UD4];
        w = b;
    }
    float4 r;
    r.x = w * m.x + (1.0f - w) * s.x;
    r.y = w * m.y + (1.0f - w) * s.y;
    r.z = w * m.z + (1.0f - w) * s.z;
    r.w = w * m.w + (1.0f - w) * s.w;
    ((float4*)bufA)[idx] = r;
    float4 ac = ((float4*)acc)[idx];
    ac.x += r.x; ac.y += r.y; ac.z += r.z; ac.w += r.w;
    ((float4*)acc)[idx] = ac;
}

// ---------------------------------------------------------------------------
// Readout: one wave per (user,item) pair; gamma = dot(acc_u, acc_i) / 16
// ---------------------------------------------------------------------------
__global__ void gamma_kernel(const float* __restrict__ acc,
                             const int* __restrict__ users,
                             const int* __restrict__ items,
                             float* __restrict__ out,
                             int B) {
    int gtid = blockIdx.x * blockDim.x + threadIdx.x;
    int wid  = gtid >> 6;
    int lane = threadIdx.x & 63;
    if (wid >= B) return;
    int u  = users[wid];
    int it = items[wid];
    float su = acc[(long long)u * D + lane];
    float si = acc[((long long)(U_N + it)) * D + lane];
    float p = su * si;
    #pragma unroll
    for (int off = 32; off > 0; off >>= 1)
        p += __shfl_down(p, off, 64);
    if (lane == 0) out[wid] = p * (1.0f / 16.0f);
}

extern "C" void kernel_launch(void* const* d_in, const int* in_sizes, int n_in,
                              void* d_out, int out_size, void* d_ws, size_t ws_size,
                              hipStream_t stream) {
    const float* user_emb    = (const float*)d_in[0];
    const float* item_emb    = (const float*)d_in[1];
    const float* symptom_emb = (const float*)d_in[2];
    const float* herb_emb    = (const float*)d_in[3];
    const float* user_lw     = (const float*)d_in[4];
    const float* item_lw     = (const float*)d_in[5];
    const float* edge_val    = (const float*)d_in[6];
    const int*   edge_row    = (const int*)d_in[7];
    const int*   edge_col    = (const int*)d_in[8];
    const int*   users       = (const int*)d_in[9];
    const int*   items       = (const int*)d_in[10];
    float* out = (float*)d_out;

    const int E = in_sizes[6];
    const int B = in_sizes[9];
    const int TPB = 256;

    // ---- fast-path workspace layout (256B-aligned carve) ----
    size_t off = 0;
    auto carve = [&](size_t bytes) -> char* {
        char* p = (char*)d_ws + off;
        off += (bytes + 255) & ~(size_t)255;
        return p;
    };
    float* buf0      = (float*)carve(NDLL * 4);
    float* buf1      = (float*)carve(NDLL * 4);
    float* acc       = (float*)carve(NDLL * 4);
    int2*  sorted    = (int2*)carve((size_t)E * 8);
    int*   counts    = (int*)carve((size_t)NN * 4);
    int*   partial   = (int*)carve((size_t)NN * 4);
    int*   row_ptr   = (int*)carve((size_t)(NN + 1) * 4);
    int*   cursor    = (int*)carve((size_t)NN * 4);
    int*   bsum      = (int*)carve(1024 * 4);
    int*   bsum_excl = (int*)carve(1024 * 4);
    const size_t fast_bytes = off;

    if (ws_size >= fast_bytes) {
        // ================= fast path: CSR gather, no atomics in SpMM ========
        int fb = (int)((ND4 + TPB - 1) / TPB);
        fuse0_kernel<<<fb, TPB, 0, stream>>>(user_emb, item_emb, symptom_emb,
                                             herb_emb, user_lw, item_lw,
                                             buf0, acc, nullptr);

        zero_counts_kernel<<<(NN + TPB - 1) / TPB, TPB, 0, stream>>>(counts);
        hist_kernel<<<(E + TPB - 1) / TPB, TPB, 0, stream>>>(edge_row, counts, E);
        scan1_kernel<<<NB, SCAN_B, 0, stream>>>(counts, partial, bsum);
        scan2_kernel<<<1, 1024, 0, stream>>>(bsum, bsum_excl);
        scan3_kernel<<<(NN + TPB - 1) / TPB, TPB, 0, stream>>>(partial, bsum_excl,
                                                               row_ptr, cursor, E);
        fill_kernel<<<(E + TPB - 1) / TPB, TPB, 0, stream>>>(edge_val, edge_row,
                                                             edge_col, cursor,
                                                             sorted, E);

        float* cur = buf0;
        float* nxt = buf1;
        int sblocks = (NN * 64 + TPB - 1) / TPB;   // 4 waves (rows) per block
        for (int layer = 1; layer <= NL; ++layer) {
            spmm_csr_fused_kernel<<<sblocks, TPB, 0, stream>>>(
                sorted, row_ptr, cur, symptom_emb, herb_emb,
                user_lw, item_lw, layer, nxt, acc);
            float* t = cur; cur = nxt; nxt = t;
        }

        int gblocks = (B * 64 + TPB - 1) / TPB;
        gamma_kernel<<<gblocks, TPB, 0, stream>>>(acc, users, items, out, B);
    } else {
        // ================= fallback: round-1 atomic scatter =================
        float* bufA = (float*)d_ws;
        float* bufB = bufA + NDLL;
        float* acc2 = bufB + NDLL;

        int fb = (int)((ND4 + TPB - 1) / TPB);
        fuse0_kernel<<<fb, TPB, 0, stream>>>(user_emb, item_emb, symptom_emb,
                                             herb_emb, user_lw, item_lw,
                                             bufA, acc2, bufB);
        for (int layer = 1; layer <= NL; ++layer) {
            long long total = (long long)E * 16;
            int blocks = (int)((total + TPB - 1) / TPB);
            spmm_scatter_kernel<<<blocks, TPB, 0, stream>>>(edge_val, edge_row,
                                                            edge_col, bufA, bufB,
                                                            total);
            int fblocks = (int)((ND4 + TPB - 1) / TPB);
            fuse_layer_kernel<<<fblocks, TPB, 0, stream>>>(symptom_emb, herb_emb,
                                                           user_lw, item_lw, layer,
                                                           bufA, bufB, acc2);
        }
        int gblocks = (B * 64 + TPB - 1) / TPB;
        gamma_kernel<<<gblocks, TPB, 0, stream>>>(acc2, users, items, out, B);
    }
}

// Round 3
// 1196.039 us; speedup vs baseline: 13.7365x; 1.4507x over previous
//
#include <hip/hip_runtime.h>

// Problem constants (match reference)
constexpr int U_N = 100000;   // users
constexpr int I_N = 100000;   // items
constexpr int D   = 64;       // latent dim
constexpr int NL  = 3;        // layers
constexpr int NN  = U_N + I_N;              // 200000 nodes
constexpr long long NDLL = (long long)NN * D;
constexpr long long ND4  = NDLL / 4;
constexpr long long UD4  = (long long)U_N * D / 4;

// Bucket sort parameters: bucket = row >> 6  (64 rows per bucket)
constexpr int BKT_SHIFT = 6;
constexpr int BKT_W     = 64;                       // rows per bucket
constexpr int NBKT      = (NN + BKT_W - 1) / BKT_W; // 3125 (NBKT*64 == NN exactly)
constexpr int ABLK      = 256;                      // blocks in binning pass

__device__ __forceinline__ float sigmoidf_(float x) {
    return 1.0f / (1.0f + expf(-x));
}

__device__ __forceinline__ float bf2f(unsigned short b) {
    return __uint_as_float((unsigned int)b << 16);
}
__device__ __forceinline__ unsigned short f2bf(float f) {
    unsigned int u = __float_as_uint(f);
    u += 0x7FFFu + ((u >> 16) & 1u);   // round-to-nearest-even
    return (unsigned short)(u >> 16);
}

// ---------------------------------------------------------------------------
// Layer-0 fusion: buf0(bf16) = fused emb, acc(fp32) = fused emb.
// Fallback variant writes fp32 bufA and zeroes bufB.
// ---------------------------------------------------------------------------
__global__ void fuse0_bf16_kernel(const float* __restrict__ user_emb,
                                  const float* __restrict__ item_emb,
                                  const float* __restrict__ symptom_emb,
                                  const float* __restrict__ herb_emb,
                                  const float* __restrict__ user_lw,
                                  const float* __restrict__ item_lw,
                                  unsigned short* __restrict__ buf0,
                                  float* __restrict__ acc) {
    long long idx = (long long)blockIdx.x * blockDim.x + threadIdx.x;
    if (idx >= ND4) return;
    float a0 = sigmoidf_(user_lw[0]);
    float b0 = sigmoidf_(item_lw[0]);
    float4 e, s;
    float w;
    if (idx < UD4) {
        e = ((const float4*)user_emb)[idx];
        s = ((const float4*)symptom_emb)[idx];
        w = a0;
    } else {
        long long j = idx - UD4;
        e = ((const float4*)item_emb)[j];
        s = ((const float4*)herb_emb)[j];
        w = b0;
    }
    float4 r;
    r.x = w * e.x + (1.0f - w) * s.x;
    r.y = w * e.y + (1.0f - w) * s.y;
    r.z = w * e.z + (1.0f - w) * s.z;
    r.w = w * e.w + (1.0f - w) * s.w;
    ((float4*)acc)[idx] = r;
    ushort4 rb;
    rb.x = f2bf(r.x); rb.y = f2bf(r.y); rb.z = f2bf(r.z); rb.w = f2bf(r.w);
    ((ushort4*)buf0)[idx] = rb;
}

// ---------------------------------------------------------------------------
// CSR build via 2-level bucket sort
// ---------------------------------------------------------------------------
__global__ void zero_bcnt_kernel(int* __restrict__ bucket_cnt) {
    int i = blockIdx.x * blockDim.x + threadIdx.x;
    if (i < NBKT) bucket_cnt[i] = 0;
}

// Pass A1: per-block LDS histogram of bucket ids, merged with global atomics
__global__ void bucket_hist_kernel(const int* __restrict__ edge_row,
                                   int* __restrict__ bucket_cnt,
                                   int E, int chunk) {
    __shared__ int h[NBKT];
    int tid = threadIdx.x;
    for (int i = tid; i < NBKT; i += blockDim.x) h[i] = 0;
    __syncthreads();
    int s = blockIdx.x * chunk;
    int eend = min(E, s + chunk);
    for (int e = s + tid; e < eend; e += blockDim.x)
        atomicAdd(&h[edge_row[e] >> BKT_SHIFT], 1);
    __syncthreads();
    for (int i = tid; i < NBKT; i += blockDim.x) {
        int c = h[i];
        if (c) atomicAdd(&bucket_cnt[i], c);
    }
}

// Scan bucket counts -> boff (exclusive), cursorA copy. Single wave.
__global__ void scan_bkt_kernel(const int* __restrict__ bucket_cnt,
                                int* __restrict__ boff,
                                int* __restrict__ cursorA, int E) {
    int lane = threadIdx.x;   // launched with 64 threads
    int base = 0;
    for (int start = 0; start < NBKT; start += 64) {
        int i = start + lane;
        int x = (i < NBKT) ? bucket_cnt[i] : 0;
        int v = x;
        #pragma unroll
        for (int off = 1; off < 64; off <<= 1) {
            int t = __shfl_up(v, off, 64);
            if (lane >= off) v += t;
        }
        int excl = base + v - x;
        if (i < NBKT) { boff[i] = excl; cursorA[i] = excl; }
        base += __shfl(v, 63, 64);
    }
    if (lane == 0) boff[NBKT] = E;
}

// Pass A2: bin edges into bucket segments. Payload packs col(18b)|rowlocal(6b).
__global__ void bin_scatter_kernel(const float* __restrict__ edge_val,
                                   const int*   __restrict__ edge_row,
                                   const int*   __restrict__ edge_col,
                                   int* __restrict__ cursorA,
                                   int2* __restrict__ binned,
                                   int E, int chunk) {
    __shared__ int h[NBKT];
    int tid = threadIdx.x;
    for (int i = tid; i < NBKT; i += blockDim.x) h[i] = 0;
    __syncthreads();
    int s = blockIdx.x * chunk;
    int eend = min(E, s + chunk);
    for (int e = s + tid; e < eend; e += blockDim.x)
        atomicAdd(&h[edge_row[e] >> BKT_SHIFT], 1);
    __syncthreads();
    // block-aggregated reservation: h[i] becomes this block's global base
    for (int i = tid; i < NBKT; i += blockDim.x) {
        int c = h[i];
        if (c) h[i] = atomicAdd(&cursorA[i], c);
    }
    __syncthreads();
    for (int e = s + tid; e < eend; e += blockDim.x) {
        int r = edge_row[e];
        int b = r >> BKT_SHIFT;
        int pos = atomicAdd(&h[b], 1);
        binned[pos] = make_int2(__float_as_int(edge_val[e]),
                                edge_col[e] | ((r & (BKT_W - 1)) << 18));
    }
}

// Pass B: one block per bucket -> exact CSR (row_ptr + sorted (val,col))
__global__ void bucket_to_csr_kernel(const int2* __restrict__ binned,
                                     const int*  __restrict__ boff,
                                     int*  __restrict__ row_ptr,
                                     int2* __restrict__ sorted, int E) {
    int b = blockIdx.x;
    int start = boff[b];
    int end   = boff[b + 1];
    __shared__ int rc[BKT_W];
    __shared__ int ex[BKT_W];
    int tid = threadIdx.x;
    if (tid < BKT_W) rc[tid] = 0;
    __syncthreads();
    for (int e = start + tid; e < end; e += blockDim.x)
        atomicAdd(&rc[binned[e].y >> 18], 1);
    __syncthreads();
    if (tid < BKT_W) {   // wave 0 scans the 64 counters
        int x = rc[tid];
        int v = x;
        #pragma unroll
        for (int off = 1; off < 64; off <<= 1) {
            int t = __shfl_up(v, off, 64);
            if (tid >= off) v += t;
        }
        int excl = v - x;
        ex[tid] = excl;
        row_ptr[(b << BKT_SHIFT) + tid] = start + excl;
    }
    __syncthreads();
    if (tid < BKT_W) rc[tid] = ex[tid];
    __syncthreads();
    for (int e = start + tid; e < end; e += blockDim.x) {
        int2 a = binned[e];
        int rl = a.y >> 18;
        int pos = start + atomicAdd(&rc[rl], 1);
        sorted[pos] = make_int2(a.x, a.y & 0x3FFFF);
    }
    if (b == 0 && tid == 0) row_ptr[NN] = E;
}

// ---------------------------------------------------------------------------
// Fused CSR SpMM (bf16 gather) + semantic mix + acc: one wave per row.
// ---------------------------------------------------------------------------
__global__ void spmm_csr_bf16_kernel(const int2* __restrict__ sorted,
                                     const int*  __restrict__ row_ptr,
                                     const unsigned short* __restrict__ src,
                                     const float* __restrict__ symptom_emb,
                                     const float* __restrict__ herb_emb,
                                     const float* __restrict__ user_lw,
                                     const float* __restrict__ item_lw,
                                     int layer,
                                     unsigned short* __restrict__ dst,
                                     float* __restrict__ acc) {
    int wid  = threadIdx.x >> 6;
    int lane = threadIdx.x & 63;                    // = dim
    int row  = blockIdx.x * (blockDim.x >> 6) + wid;
    if (row >= NN) return;

    int start = row_ptr[row];
    int end   = row_ptr[row + 1];

    float s0 = 0.f, s1 = 0.f, s2 = 0.f, s3 = 0.f;
    int e = start;
    for (; e + 4 <= end; e += 4) {
        int2 a0 = sorted[e + 0];
        int2 a1 = sorted[e + 1];
        int2 a2 = sorted[e + 2];
        int2 a3 = sorted[e + 3];
        float g0 = bf2f(src[((size_t)a0.y << 6) | lane]);
        float g1 = bf2f(src[((size_t)a1.y << 6) | lane]);
        float g2 = bf2f(src[((size_t)a2.y << 6) | lane]);
        float g3 = bf2f(src[((size_t)a3.y << 6) | lane]);
        s0 += __int_as_float(a0.x) * g0;
        s1 += __int_as_float(a1.x) * g1;
        s2 += __int_as_float(a2.x) * g2;
        s3 += __int_as_float(a3.x) * g3;
    }
    for (; e < end; ++e) {
        int2 a = sorted[e];
        s0 += __int_as_float(a.x) * bf2f(src[((size_t)a.y << 6) | lane]);
    }
    float sum = (s0 + s1) + (s2 + s3);

    float w, sem;
    if (row < U_N) {
        w = sigmoidf_(user_lw[layer]);
        sem = symptom_emb[((size_t)row << 6) | lane];
    } else {
        w = sigmoidf_(item_lw[layer]);
        sem = herb_emb[((size_t)(row - U_N) << 6) | lane];
    }
    float r = w * sum + (1.0f - w) * sem;
    size_t o = ((size_t)row << 6) | lane;
    dst[o] = f2bf(r);
    acc[o] += r;
}

// ---------------------------------------------------------------------------
// Readout: one wave per (user,item) pair; gamma = dot(acc_u, acc_i) / 16
// ---------------------------------------------------------------------------
__global__ void gamma_kernel(const float* __restrict__ acc,
                             const int* __restrict__ users,
                             const int* __restrict__ items,
                             float* __restrict__ out,
                             int B) {
    int gtid = blockIdx.x * blockDim.x + threadIdx.x;
    int wid  = gtid >> 6;
    int lane = threadIdx.x & 63;
    if (wid >= B) return;
    int u  = users[wid];
    int it = items[wid];
    float su = acc[(long long)u * D + lane];
    float si = acc[((long long)(U_N + it)) * D + lane];
    float p = su * si;
    #pragma unroll
    for (int off = 32; off > 0; off >>= 1)
        p += __shfl_down(p, off, 64);
    if (lane == 0) out[wid] = p * (1.0f / 16.0f);
}

// ---------------------------------------------------------------------------
// Fallback (round-1 atomic scatter) kernels, used only if ws too small
// ---------------------------------------------------------------------------
__global__ void fuse0_kernel(const float* __restrict__ user_emb,
                             const float* __restrict__ item_emb,
                             const float* __restrict__ symptom_emb,
                             const float* __restrict__ herb_emb,
                             const float* __restrict__ user_lw,
                             const float* __restrict__ item_lw,
                             float* __restrict__ bufA,
                             float* __restrict__ acc,
                             float* __restrict__ bufB) {
    long long idx = (long long)blockIdx.x * blockDim.x + threadIdx.x;
    if (idx >= ND4) return;
    float a0 = sigmoidf_(user_lw[0]);
    float b0 = sigmoidf_(item_lw[0]);
    float4 e, s;
    float w;
    if (idx < UD4) {
        e = ((const float4*)user_emb)[idx];
        s = ((const float4*)symptom_emb)[idx];
        w = a0;
    } else {
        long long j = idx - UD4;
        e = ((const float4*)item_emb)[j];
        s = ((const float4*)herb_emb)[j];
        w = b0;
    }
    float4 r;
    r.x = w * e.x + (1.0f - w) * s.x;
    r.y = w * e.y + (1.0f - w) * s.y;
    r.z = w * e.z + (1.0f - w) * s.z;
    r.w = w * e.w + (1.0f - w) * s.w;
    ((float4*)bufA)[idx] = r;
    ((float4*)acc)[idx]  = r;
    float4 z; z.x = z.y = z.z = z.w = 0.0f;
    ((float4*)bufB)[idx] = z;
}

__global__ void spmm_scatter_kernel(const float* __restrict__ edge_val,
                                    const int*   __restrict__ edge_row,
                                    const int*   __restrict__ edge_col,
                                    const float* __restrict__ src,
                                    float*       __restrict__ dst,
                                    long long total) {
    long long idx = (long long)blockIdx.x * blockDim.x + threadIdx.x;
    if (idx >= total) return;
    long long e = idx >> 4;
    int       q = (int)(idx & 15);
    int r = edge_row[e];
    int c = edge_col[e];
    float v = edge_val[e];
    float4 x = *(const float4*)(src + (long long)c * D + q * 4);
    float* d = dst + (long long)r * D + q * 4;
    atomicAdd(d + 0, v * x.x);
    atomicAdd(d + 1, v * x.y);
    atomicAdd(d + 2, v * x.z);
    atomicAdd(d + 3, v * x.w);
}

__global__ void fuse_layer_kernel(const float* __restrict__ symptom_emb,
                                  const float* __restrict__ herb_emb,
                                  const float* __restrict__ user_lw,
                                  const float* __restrict__ item_lw,
                                  int layer,
                                  float* __restrict__ bufA,
                                  float* __restrict__ bufB,
                                  float* __restrict__ acc) {
    long long idx = (long long)blockIdx.x * blockDim.x + threadIdx.x;
    if (idx >= ND4) return;
    float a = sigmoidf_(user_lw[layer]);
    float b = sigmoidf_(item_lw[layer]);
    float4 m = ((float4*)bufB)[idx];
    float4 z; z.x = z.y = z.z = z.w = 0.0f;
    ((float4*)bufB)[idx] = z;
    float4 s;
    float w;
    if (idx < UD4) {
        s = ((const float4*)symptom_emb)[idx];
        w = a;
    } else {
        s = ((const float4*)herb_emb)[idx - UD4];
        w = b;
    }
    float4 r;
    r.x = w * m.x + (1.0f - w) * s.x;
    r.y = w * m.y + (1.0f - w) * s.y;
    r.z = w * m.z + (1.0f - w) * s.z;
    r.w = w * m.w + (1.0f - w) * s.w;
    ((float4*)bufA)[idx] = r;
    float4 ac = ((float4*)acc)[idx];
    ac.x += r.x; ac.y += r.y; ac.z += r.z; ac.w += r.w;
    ((float4*)acc)[idx] = ac;
}

extern "C" void kernel_launch(void* const* d_in, const int* in_sizes, int n_in,
                              void* d_out, int out_size, void* d_ws, size_t ws_size,
                              hipStream_t stream) {
    const float* user_emb    = (const float*)d_in[0];
    const float* item_emb    = (const float*)d_in[1];
    const float* symptom_emb = (const float*)d_in[2];
    const float* herb_emb    = (const float*)d_in[3];
    const float* user_lw     = (const float*)d_in[4];
    const float* item_lw     = (const float*)d_in[5];
    const float* edge_val    = (const float*)d_in[6];
    const int*   edge_row    = (const int*)d_in[7];
    const int*   edge_col    = (const int*)d_in[8];
    const int*   users       = (const int*)d_in[9];
    const int*   items       = (const int*)d_in[10];
    float* out = (float*)d_out;

    const int E = in_sizes[6];
    const int B = in_sizes[9];
    const int TPB = 256;

    // ---- fast-path workspace layout (256B-aligned carve) ----
    size_t off = 0;
    auto carve = [&](size_t bytes) -> char* {
        char* p = (char*)d_ws + off;
        off += (bytes + 255) & ~(size_t)255;
        return p;
    };
    float*          acc     = (float*)carve(NDLL * 4);
    unsigned short* buf0    = (unsigned short*)carve(NDLL * 2);
    unsigned short* buf1    = (unsigned short*)carve(NDLL * 2);
    int2*           binned  = (int2*)carve((size_t)E * 8);
    int2*           sorted  = (int2*)carve((size_t)E * 8);
    int*            row_ptr = (int*)carve((size_t)(NN + 1) * 4);
    int*            bcnt    = (int*)carve((size_t)NBKT * 4);
    int*            boff    = (int*)carve((size_t)(NBKT + 1) * 4);
    int*            cursorA = (int*)carve((size_t)NBKT * 4);
    const size_t fast_bytes = off;

    if (ws_size >= fast_bytes) {
        // ================= fast path: bucket-sorted CSR + bf16 gather =======
        int fb = (int)((ND4 + TPB - 1) / TPB);
        fuse0_bf16_kernel<<<fb, TPB, 0, stream>>>(user_emb, item_emb, symptom_emb,
                                                  herb_emb, user_lw, item_lw,
                                                  buf0, acc);

        int chunk = (E + ABLK - 1) / ABLK;
        zero_bcnt_kernel<<<(NBKT + TPB - 1) / TPB, TPB, 0, stream>>>(bcnt);
        bucket_hist_kernel<<<ABLK, TPB, 0, stream>>>(edge_row, bcnt, E, chunk);
        scan_bkt_kernel<<<1, 64, 0, stream>>>(bcnt, boff, cursorA, E);
        bin_scatter_kernel<<<ABLK, TPB, 0, stream>>>(edge_val, edge_row, edge_col,
                                                     cursorA, binned, E, chunk);
        bucket_to_csr_kernel<<<NBKT, TPB, 0, stream>>>(binned, boff, row_ptr,
                                                       sorted, E);

        unsigned short* cur = buf0;
        unsigned short* nxt = buf1;
        int sblocks = (NN * 64 + TPB - 1) / TPB;   // 4 rows (waves) per block
        for (int layer = 1; layer <= NL; ++layer) {
            spmm_csr_bf16_kernel<<<sblocks, TPB, 0, stream>>>(
                sorted, row_ptr, cur, symptom_emb, herb_emb,
                user_lw, item_lw, layer, nxt, acc);
            unsigned short* t = cur; cur = nxt; nxt = t;
        }

        int gblocks = (B * 64 + TPB - 1) / TPB;
        gamma_kernel<<<gblocks, TPB, 0, stream>>>(acc, users, items, out, B);
    } else {
        // ================= fallback: atomic scatter =========================
        float* bufA = (float*)d_ws;
        float* bufB = bufA + NDLL;
        float* acc2 = bufB + NDLL;

        int fb = (int)((ND4 + TPB - 1) / TPB);
        fuse0_kernel<<<fb, TPB, 0, stream>>>(user_emb, item_emb, symptom_emb,
                                             herb_emb, user_lw, item_lw,
                                             bufA, acc2, bufB);
        for (int layer = 1; layer <= NL; ++layer) {
            long long total = (long long)E * 16;
            int blocks = (int)((total + TPB - 1) / TPB);
            spmm_scatter_kernel<<<blocks, TPB, 0, stream>>>(edge_val, edge_row,
                                                            edge_col, bufA, bufB,
                                                            total);
            int fblocks = (int)((ND4 + TPB - 1) / TPB);
            fuse_layer_kernel<<<fblocks, TPB, 0, stream>>>(symptom_emb, herb_emb,
                                                           user_lw, item_lw, layer,
                                                           bufA, bufB, acc2);
        }
        int gblocks = (B * 64 + TPB - 1) / TPB;
        gamma_kernel<<<gblocks, TPB, 0, stream>>>(acc2, users, items, out, B);
    }
}

// Round 4
// 979.943 us; speedup vs baseline: 16.7656x; 1.2205x over previous
//
#include <hip/hip_runtime.h>

// Problem constants (match reference)
constexpr int U_N = 100000;   // users
constexpr int I_N = 100000;   // items
constexpr int D   = 64;       // latent dim
constexpr int NL  = 3;        // layers
constexpr int NN  = U_N + I_N;              // 200000 nodes
constexpr long long NDLL = (long long)NN * D;
constexpr long long ND4  = NDLL / 4;
constexpr long long UD4  = (long long)U_N * D / 4;

// Bucket sort parameters: bucket = row >> 6  (64 rows per bucket)
constexpr int BKT_SHIFT = 6;
constexpr int BKT_W     = 64;                       // rows per bucket
constexpr int NBKT      = (NN + BKT_W - 1) / BKT_W; // 3125 (NBKT*64 == NN exactly)
constexpr int ABLK      = 256;                      // blocks in binning pass

__device__ __forceinline__ float sigmoidf_(float x) {
    return 1.0f / (1.0f + expf(-x));
}

__device__ __forceinline__ float bf2f(unsigned short b) {
    return __uint_as_float((unsigned int)b << 16);
}
__device__ __forceinline__ unsigned short f2bf(float f) {
    unsigned int u = __float_as_uint(f);
    u += 0x7FFFu + ((u >> 16) & 1u);   // round-to-nearest-even
    return (unsigned short)(u >> 16);
}

// ---------------------------------------------------------------------------
// Layer-0 fusion: buf0(bf16) = fused emb, acc(fp32) = fused emb.
// ---------------------------------------------------------------------------
__global__ void fuse0_bf16_kernel(const float* __restrict__ user_emb,
                                  const float* __restrict__ item_emb,
                                  const float* __restrict__ symptom_emb,
                                  const float* __restrict__ herb_emb,
                                  const float* __restrict__ user_lw,
                                  const float* __restrict__ item_lw,
                                  unsigned short* __restrict__ buf0,
                                  float* __restrict__ acc) {
    long long idx = (long long)blockIdx.x * blockDim.x + threadIdx.x;
    if (idx >= ND4) return;
    float a0 = sigmoidf_(user_lw[0]);
    float b0 = sigmoidf_(item_lw[0]);
    float4 e, s;
    float w;
    if (idx < UD4) {
        e = ((const float4*)user_emb)[idx];
        s = ((const float4*)symptom_emb)[idx];
        w = a0;
    } else {
        long long j = idx - UD4;
        e = ((const float4*)item_emb)[j];
        s = ((const float4*)herb_emb)[j];
        w = b0;
    }
    float4 r;
    r.x = w * e.x + (1.0f - w) * s.x;
    r.y = w * e.y + (1.0f - w) * s.y;
    r.z = w * e.z + (1.0f - w) * s.z;
    r.w = w * e.w + (1.0f - w) * s.w;
    ((float4*)acc)[idx] = r;
    ushort4 rb;
    rb.x = f2bf(r.x); rb.y = f2bf(r.y); rb.z = f2bf(r.z); rb.w = f2bf(r.w);
    ((ushort4*)buf0)[idx] = rb;
}

// ---------------------------------------------------------------------------
// CSR build via 2-level bucket sort
// ---------------------------------------------------------------------------
__global__ void zero_bcnt_kernel(int* __restrict__ bucket_cnt) {
    int i = blockIdx.x * blockDim.x + threadIdx.x;
    if (i < NBKT) bucket_cnt[i] = 0;
}

// Pass A1: per-block LDS histogram of bucket ids, merged with global atomics
__global__ void bucket_hist_kernel(const int* __restrict__ edge_row,
                                   int* __restrict__ bucket_cnt,
                                   int E, int chunk) {
    __shared__ int h[NBKT];
    int tid = threadIdx.x;
    for (int i = tid; i < NBKT; i += blockDim.x) h[i] = 0;
    __syncthreads();
    int s = blockIdx.x * chunk;
    int eend = min(E, s + chunk);
    for (int e = s + tid; e < eend; e += blockDim.x)
        atomicAdd(&h[edge_row[e] >> BKT_SHIFT], 1);
    __syncthreads();
    for (int i = tid; i < NBKT; i += blockDim.x) {
        int c = h[i];
        if (c) atomicAdd(&bucket_cnt[i], c);
    }
}

// Scan bucket counts -> boff (exclusive), cursorA copy. One 1024-thread block.
__global__ void scan_bkt_kernel(const int* __restrict__ bucket_cnt,
                                int* __restrict__ boff,
                                int* __restrict__ cursorA, int E) {
    __shared__ int sm[1024];
    int tid = threadIdx.x;
    int i0 = tid * 4;       // 4 consecutive buckets per thread (4096 >= NBKT)
    int c[4];
    int ssum = 0;
    #pragma unroll
    for (int j = 0; j < 4; ++j) {
        int i = i0 + j;
        c[j] = (i < NBKT) ? bucket_cnt[i] : 0;
        ssum += c[j];
    }
    sm[tid] = ssum;
    __syncthreads();
    for (int off = 1; off < 1024; off <<= 1) {
        int t = (tid >= off) ? sm[tid - off] : 0;
        __syncthreads();
        sm[tid] += t;
        __syncthreads();
    }
    int base = sm[tid] - ssum;   // exclusive prefix of this thread's chunk
    #pragma unroll
    for (int j = 0; j < 4; ++j) {
        int i = i0 + j;
        if (i < NBKT) { boff[i] = base; cursorA[i] = base; }
        base += c[j];
    }
    if (tid == 0) boff[NBKT] = E;
}

// Pass A2: bin edges into bucket segments. Payload packs col(18b)|rowlocal(6b).
__global__ void bin_scatter_kernel(const float* __restrict__ edge_val,
                                   const int*   __restrict__ edge_row,
                                   const int*   __restrict__ edge_col,
                                   int* __restrict__ cursorA,
                                   int2* __restrict__ binned,
                                   int E, int chunk) {
    __shared__ int h[NBKT];
    int tid = threadIdx.x;
    for (int i = tid; i < NBKT; i += blockDim.x) h[i] = 0;
    __syncthreads();
    int s = blockIdx.x * chunk;
    int eend = min(E, s + chunk);
    for (int e = s + tid; e < eend; e += blockDim.x)
        atomicAdd(&h[edge_row[e] >> BKT_SHIFT], 1);
    __syncthreads();
    // block-aggregated reservation: h[i] becomes this block's global base
    for (int i = tid; i < NBKT; i += blockDim.x) {
        int c = h[i];
        if (c) h[i] = atomicAdd(&cursorA[i], c);
    }
    __syncthreads();
    for (int e = s + tid; e < eend; e += blockDim.x) {
        int r = edge_row[e];
        int b = r >> BKT_SHIFT;
        int pos = atomicAdd(&h[b], 1);
        binned[pos] = make_int2(__float_as_int(edge_val[e]),
                                edge_col[e] | ((r & (BKT_W - 1)) << 18));
    }
}

// Pass B: one block per bucket -> exact CSR (row_ptr + sorted (val,col))
__global__ void bucket_to_csr_kernel(const int2* __restrict__ binned,
                                     const int*  __restrict__ boff,
                                     int*  __restrict__ row_ptr,
                                     int2* __restrict__ sorted, int E) {
    int b = blockIdx.x;
    int start = boff[b];
    int end   = boff[b + 1];
    __shared__ int rc[BKT_W];
    __shared__ int ex[BKT_W];
    int tid = threadIdx.x;
    if (tid < BKT_W) rc[tid] = 0;
    __syncthreads();
    for (int e = start + tid; e < end; e += blockDim.x)
        atomicAdd(&rc[binned[e].y >> 18], 1);
    __syncthreads();
    if (tid < BKT_W) {   // wave 0 scans the 64 counters
        int x = rc[tid];
        int v = x;
        #pragma unroll
        for (int off = 1; off < 64; off <<= 1) {
            int t = __shfl_up(v, off, 64);
            if (tid >= off) v += t;
        }
        int excl = v - x;
        ex[tid] = excl;
        row_ptr[(b << BKT_SHIFT) + tid] = start + excl;
    }
    __syncthreads();
    if (tid < BKT_W) rc[tid] = ex[tid];
    __syncthreads();
    for (int e = start + tid; e < end; e += blockDim.x) {
        int2 a = binned[e];
        int rl = a.y >> 18;
        int pos = start + atomicAdd(&rc[rl], 1);
        sorted[pos] = make_int2(a.x, a.y & 0x3FFFF);
    }
    if (b == 0 && tid == 0) row_ptr[NN] = E;
}

// ---------------------------------------------------------------------------
// Fused CSR SpMM (bf16 gather) + semantic mix + acc.
// One wave per row; lane = (g,p): g = edge slot (4), p = dim quad (16).
// Lane gathers ushort4 (4 bf16 dims) of edge e+g's source row: one dwordx2
// instruction moves 512 B and covers 4 edges.
// ---------------------------------------------------------------------------
__global__ void spmm_csr_bf16_kernel(const int2* __restrict__ sorted,
                                     const int*  __restrict__ row_ptr,
                                     const unsigned short* __restrict__ src,
                                     const float* __restrict__ symptom_emb,
                                     const float* __restrict__ herb_emb,
                                     const float* __restrict__ user_lw,
                                     const float* __restrict__ item_lw,
                                     int layer,
                                     unsigned short* __restrict__ dst,
                                     float* __restrict__ acc) {
    int wid  = threadIdx.x >> 6;
    int lane = threadIdx.x & 63;
    int row  = blockIdx.x * (blockDim.x >> 6) + wid;
    if (row >= NN) return;
    int g = lane >> 4;        // edge slot 0..3
    int p = lane & 15;        // dim quad 0..15 (dims 4p..4p+3)

    int start = row_ptr[row];
    int end   = row_ptr[row + 1];

    const ushort4* src4 = (const ushort4*)src;   // row = 16 ushort4

    float4 s0 = {0.f, 0.f, 0.f, 0.f};
    float4 s1 = {0.f, 0.f, 0.f, 0.f};
    int e = start;
    for (; e + 8 <= end; e += 8) {
        int2 a0 = sorted[e + g];
        int2 a1 = sorted[e + 4 + g];
        ushort4 u0 = src4[((size_t)(unsigned)a0.y << 4) + p];
        ushort4 u1 = src4[((size_t)(unsigned)a1.y << 4) + p];
        float v0 = __int_as_float(a0.x);
        float v1 = __int_as_float(a1.x);
        s0.x += v0 * bf2f(u0.x); s0.y += v0 * bf2f(u0.y);
        s0.z += v0 * bf2f(u0.z); s0.w += v0 * bf2f(u0.w);
        s1.x += v1 * bf2f(u1.x); s1.y += v1 * bf2f(u1.y);
        s1.z += v1 * bf2f(u1.z); s1.w += v1 * bf2f(u1.w);
    }
    for (; e < end; e += 4) {
        int idx = e + g;
        int2 a = (idx < end) ? sorted[idx] : make_int2(0, 0);
        ushort4 u = src4[((size_t)(unsigned)a.y << 4) + p];
        float v = __int_as_float(a.x);      // 0.0f for tail slots
        s0.x += v * bf2f(u.x); s0.y += v * bf2f(u.y);
        s0.z += v * bf2f(u.z); s0.w += v * bf2f(u.w);
    }
    float4 s;
    s.x = s0.x + s1.x; s.y = s0.y + s1.y;
    s.z = s0.z + s1.z; s.w = s0.w + s1.w;

    // reduce the 4 edge slots: lanes {p, p+16, p+32, p+48} hold partials
    #pragma unroll
    for (int m = 16; m < 64; m <<= 1) {
        s.x += __shfl_xor(s.x, m, 64);
        s.y += __shfl_xor(s.y, m, 64);
        s.z += __shfl_xor(s.z, m, 64);
        s.w += __shfl_xor(s.w, m, 64);
    }

    if (lane < 16) {   // lanes 0..15 own dim quads of this row
        size_t o = ((size_t)row << 6) + ((size_t)p << 2);
        float wgt;
        float4 sv;
        if (row < U_N) {
            wgt = sigmoidf_(user_lw[layer]);
            sv = *(const float4*)(symptom_emb + o);
        } else {
            wgt = sigmoidf_(item_lw[layer]);
            sv = *(const float4*)(herb_emb + o - ((size_t)U_N << 6));
        }
        float4 r;
        r.x = wgt * s.x + (1.0f - wgt) * sv.x;
        r.y = wgt * s.y + (1.0f - wgt) * sv.y;
        r.z = wgt * s.z + (1.0f - wgt) * sv.z;
        r.w = wgt * s.w + (1.0f - wgt) * sv.w;
        ushort4 rb;
        rb.x = f2bf(r.x); rb.y = f2bf(r.y); rb.z = f2bf(r.z); rb.w = f2bf(r.w);
        *(ushort4*)(dst + o) = rb;
        float4 ac = *(const float4*)(acc + o);
        ac.x += r.x; ac.y += r.y; ac.z += r.z; ac.w += r.w;
        *(float4*)(acc + o) = ac;
    }
}

// ---------------------------------------------------------------------------
// Readout: one wave per (user,item) pair; gamma = dot(acc_u, acc_i) / 16
// ---------------------------------------------------------------------------
__global__ void gamma_kernel(const float* __restrict__ acc,
                             const int* __restrict__ users,
                             const int* __restrict__ items,
                             float* __restrict__ out,
                             int B) {
    int gtid = blockIdx.x * blockDim.x + threadIdx.x;
    int wid  = gtid >> 6;
    int lane = threadIdx.x & 63;
    if (wid >= B) return;
    int u  = users[wid];
    int it = items[wid];
    float su = acc[(long long)u * D + lane];
    float si = acc[((long long)(U_N + it)) * D + lane];
    float p = su * si;
    #pragma unroll
    for (int off = 32; off > 0; off >>= 1)
        p += __shfl_down(p, off, 64);
    if (lane == 0) out[wid] = p * (1.0f / 16.0f);
}

// ---------------------------------------------------------------------------
// Fallback (round-1 atomic scatter) kernels, used only if ws too small
// ---------------------------------------------------------------------------
__global__ void fuse0_kernel(const float* __restrict__ user_emb,
                             const float* __restrict__ item_emb,
                             const float* __restrict__ symptom_emb,
                             const float* __restrict__ herb_emb,
                             const float* __restrict__ user_lw,
                             const float* __restrict__ item_lw,
                             float* __restrict__ bufA,
                             float* __restrict__ acc,
                             float* __restrict__ bufB) {
    long long idx = (long long)blockIdx.x * blockDim.x + threadIdx.x;
    if (idx >= ND4) return;
    float a0 = sigmoidf_(user_lw[0]);
    float b0 = sigmoidf_(item_lw[0]);
    float4 e, s;
    float w;
    if (idx < UD4) {
        e = ((const float4*)user_emb)[idx];
        s = ((const float4*)symptom_emb)[idx];
        w = a0;
    } else {
        long long j = idx - UD4;
        e = ((const float4*)item_emb)[j];
        s = ((const float4*)herb_emb)[j];
        w = b0;
    }
    float4 r;
    r.x = w * e.x + (1.0f - w) * s.x;
    r.y = w * e.y + (1.0f - w) * s.y;
    r.z = w * e.z + (1.0f - w) * s.z;
    r.w = w * e.w + (1.0f - w) * s.w;
    ((float4*)bufA)[idx] = r;
    ((float4*)acc)[idx]  = r;
    float4 z; z.x = z.y = z.z = z.w = 0.0f;
    ((float4*)bufB)[idx] = z;
}

__global__ void spmm_scatter_kernel(const float* __restrict__ edge_val,
                                    const int*   __restrict__ edge_row,
                                    const int*   __restrict__ edge_col,
                                    const float* __restrict__ src,
                                    float*       __restrict__ dst,
                                    long long total) {
    long long idx = (long long)blockIdx.x * blockDim.x + threadIdx.x;
    if (idx >= total) return;
    long long e = idx >> 4;
    int       q = (int)(idx & 15);
    int r = edge_row[e];
    int c = edge_col[e];
    float v = edge_val[e];
    float4 x = *(const float4*)(src + (long long)c * D + q * 4);
    float* d = dst + (long long)r * D + q * 4;
    atomicAdd(d + 0, v * x.x);
    atomicAdd(d + 1, v * x.y);
    atomicAdd(d + 2, v * x.z);
    atomicAdd(d + 3, v * x.w);
}

__global__ void fuse_layer_kernel(const float* __restrict__ symptom_emb,
                                  const float* __restrict__ herb_emb,
                                  const float* __restrict__ user_lw,
                                  const float* __restrict__ item_lw,
                                  int layer,
                                  float* __restrict__ bufA,
                                  float* __restrict__ bufB,
                                  float* __restrict__ acc) {
    long long idx = (long long)blockIdx.x * blockDim.x + threadIdx.x;
    if (idx >= ND4) return;
    float a = sigmoidf_(user_lw[layer]);
    float b = sigmoidf_(item_lw[layer]);
    float4 m = ((float4*)bufB)[idx];
    float4 z; z.x = z.y = z.z = z.w = 0.0f;
    ((float4*)bufB)[idx] = z;
    float4 s;
    float w;
    if (idx < UD4) {
        s = ((const float4*)symptom_emb)[idx];
        w = a;
    } else {
        s = ((const float4*)herb_emb)[idx - UD4];
        w = b;
    }
    float4 r;
    r.x = w * m.x + (1.0f - w) * s.x;
    r.y = w * m.y + (1.0f - w) * s.y;
    r.z = w * m.z + (1.0f - w) * s.z;
    r.w = w * m.w + (1.0f - w) * s.w;
    ((float4*)bufA)[idx] = r;
    float4 ac = ((float4*)acc)[idx];
    ac.x += r.x; ac.y += r.y; ac.z += r.z; ac.w += r.w;
    ((float4*)acc)[idx] = ac;
}

extern "C" void kernel_launch(void* const* d_in, const int* in_sizes, int n_in,
                              void* d_out, int out_size, void* d_ws, size_t ws_size,
                              hipStream_t stream) {
    const float* user_emb    = (const float*)d_in[0];
    const float* item_emb    = (const float*)d_in[1];
    const float* symptom_emb = (const float*)d_in[2];
    const float* herb_emb    = (const float*)d_in[3];
    const float* user_lw     = (const float*)d_in[4];
    const float* item_lw     = (const float*)d_in[5];
    const float* edge_val    = (const float*)d_in[6];
    const int*   edge_row    = (const int*)d_in[7];
    const int*   edge_col    = (const int*)d_in[8];
    const int*   users       = (const int*)d_in[9];
    const int*   items       = (const int*)d_in[10];
    float* out = (float*)d_out;

    const int E = in_sizes[6];
    const int B = in_sizes[9];
    const int TPB = 256;

    // ---- fast-path workspace layout (256B-aligned carve) ----
    size_t off = 0;
    auto carve = [&](size_t bytes) -> char* {
        char* p = (char*)d_ws + off;
        off += (bytes + 255) & ~(size_t)255;
        return p;
    };
    float*          acc     = (float*)carve(NDLL * 4);
    unsigned short* buf0    = (unsigned short*)carve(NDLL * 2);
    unsigned short* buf1    = (unsigned short*)carve(NDLL * 2);
    int2*           binned  = (int2*)carve((size_t)E * 8);
    int2*           sorted  = (int2*)carve((size_t)E * 8);
    int*            row_ptr = (int*)carve((size_t)(NN + 1) * 4);
    int*            bcnt    = (int*)carve((size_t)NBKT * 4);
    int*            boff    = (int*)carve((size_t)(NBKT + 1) * 4);
    int*            cursorA = (int*)carve((size_t)NBKT * 4);
    const size_t fast_bytes = off;

    if (ws_size >= fast_bytes) {
        // ================= fast path: bucket-sorted CSR + bf16 gather =======
        int fb = (int)((ND4 + TPB - 1) / TPB);
        fuse0_bf16_kernel<<<fb, TPB, 0, stream>>>(user_emb, item_emb, symptom_emb,
                                                  herb_emb, user_lw, item_lw,
                                                  buf0, acc);

        int chunk = (E + ABLK - 1) / ABLK;
        zero_bcnt_kernel<<<(NBKT + TPB - 1) / TPB, TPB, 0, stream>>>(bcnt);
        bucket_hist_kernel<<<ABLK, TPB, 0, stream>>>(edge_row, bcnt, E, chunk);
        scan_bkt_kernel<<<1, 1024, 0, stream>>>(bcnt, boff, cursorA, E);
        bin_scatter_kernel<<<ABLK, TPB, 0, stream>>>(edge_val, edge_row, edge_col,
                                                     cursorA, binned, E, chunk);
        bucket_to_csr_kernel<<<NBKT, TPB, 0, stream>>>(binned, boff, row_ptr,
                                                       sorted, E);

        unsigned short* cur = buf0;
        unsigned short* nxt = buf1;
        int sblocks = (NN * 64 + TPB - 1) / TPB;   // 4 rows (waves) per block
        for (int layer = 1; layer <= NL; ++layer) {
            spmm_csr_bf16_kernel<<<sblocks, TPB, 0, stream>>>(
                sorted, row_ptr, cur, symptom_emb, herb_emb,
                user_lw, item_lw, layer, nxt, acc);
            unsigned short* t = cur; cur = nxt; nxt = t;
        }

        int gblocks = (B * 64 + TPB - 1) / TPB;
        gamma_kernel<<<gblocks, TPB, 0, stream>>>(acc, users, items, out, B);
    } else {
        // ================= fallback: atomic scatter =========================
        float* bufA = (float*)d_ws;
        float* bufB = bufA + NDLL;
        float* acc2 = bufB + NDLL;

        int fb = (int)((ND4 + TPB - 1) / TPB);
        fuse0_kernel<<<fb, TPB, 0, stream>>>(user_emb, item_emb, symptom_emb,
                                             herb_emb, user_lw, item_lw,
                                             bufA, acc2, bufB);
        for (int layer = 1; layer <= NL; ++layer) {
            long long total = (long long)E * 16;
            int blocks = (int)((total + TPB - 1) / TPB);
            spmm_scatter_kernel<<<blocks, TPB, 0, stream>>>(edge_val, edge_row,
                                                            edge_col, bufA, bufB,
                                                            total);
            int fblocks = (int)((ND4 + TPB - 1) / TPB);
            fuse_layer_kernel<<<fblocks, TPB, 0, stream>>>(symptom_emb, herb_emb,
                                                           user_lw, item_lw, layer,
                                                           bufA, bufB, acc2);
        }
        int gblocks = (B * 64 + TPB - 1) / TPB;
        gamma_kernel<<<gblocks, TPB, 0, stream>>>(acc2, users, items, out, B);
    }
}

// Round 5
// 916.473 us; speedup vs baseline: 17.9267x; 1.0693x over previous
//
#include <hip/hip_runtime.h>

// Problem constants (match reference)
constexpr int U_N = 100000;   // users
constexpr int I_N = 100000;   // items
constexpr int D   = 64;       // latent dim
constexpr int NL  = 3;        // layers
constexpr int NN  = U_N + I_N;              // 200000 nodes
constexpr long long NDLL = (long long)NN * D;
constexpr long long ND4  = NDLL / 4;
constexpr long long UD4  = (long long)U_N * D / 4;

// Bucket sort parameters: bucket = row >> 8  (256 rows per bucket)
constexpr int BKT_SHIFT = 8;
constexpr int BKT_W     = 256;                      // rows per bucket
constexpr int NBKT      = (NN + BKT_W - 1) / BKT_W; // 782
constexpr int ABLK      = 1024;                     // blocks in binning pass

__device__ __forceinline__ float sigmoidf_(float x) {
    return 1.0f / (1.0f + expf(-x));
}

__device__ __forceinline__ float bf2f(unsigned short b) {
    return __uint_as_float((unsigned int)b << 16);
}
__device__ __forceinline__ unsigned short f2bf(float f) {
    unsigned int u = __float_as_uint(f);
    u += 0x7FFFu + ((u >> 16) & 1u);   // round-to-nearest-even
    return (unsigned short)(u >> 16);
}

// ---------------------------------------------------------------------------
// Layer-0 fusion: e0b(bf16) = fused emb (gather source), e0f(fp32) = same
// (read by gamma at full precision).
// ---------------------------------------------------------------------------
__global__ void fuse0_bf16_kernel(const float* __restrict__ user_emb,
                                  const float* __restrict__ item_emb,
                                  const float* __restrict__ symptom_emb,
                                  const float* __restrict__ herb_emb,
                                  const float* __restrict__ user_lw,
                                  const float* __restrict__ item_lw,
                                  unsigned short* __restrict__ e0b,
                                  float* __restrict__ e0f) {
    long long idx = (long long)blockIdx.x * blockDim.x + threadIdx.x;
    if (idx >= ND4) return;
    float a0 = sigmoidf_(user_lw[0]);
    float b0 = sigmoidf_(item_lw[0]);
    float4 e, s;
    float w;
    if (idx < UD4) {
        e = ((const float4*)user_emb)[idx];
        s = ((const float4*)symptom_emb)[idx];
        w = a0;
    } else {
        long long j = idx - UD4;
        e = ((const float4*)item_emb)[j];
        s = ((const float4*)herb_emb)[j];
        w = b0;
    }
    float4 r;
    r.x = w * e.x + (1.0f - w) * s.x;
    r.y = w * e.y + (1.0f - w) * s.y;
    r.z = w * e.z + (1.0f - w) * s.z;
    r.w = w * e.w + (1.0f - w) * s.w;
    ((float4*)e0f)[idx] = r;
    ushort4 rb;
    rb.x = f2bf(r.x); rb.y = f2bf(r.y); rb.z = f2bf(r.z); rb.w = f2bf(r.w);
    ((ushort4*)e0b)[idx] = rb;
}

// ---------------------------------------------------------------------------
// CSR build via 2-level bucket sort (256 rows per bucket)
// ---------------------------------------------------------------------------
__global__ void zero_bcnt_kernel(int* __restrict__ bucket_cnt) {
    int i = blockIdx.x * blockDim.x + threadIdx.x;
    if (i < NBKT) bucket_cnt[i] = 0;
}

// Pass A1: per-block LDS histogram of bucket ids, merged with global atomics
__global__ void bucket_hist_kernel(const int* __restrict__ edge_row,
                                   int* __restrict__ bucket_cnt,
                                   int E, int chunk) {
    __shared__ int h[NBKT];
    int tid = threadIdx.x;
    for (int i = tid; i < NBKT; i += blockDim.x) h[i] = 0;
    __syncthreads();
    int s = blockIdx.x * chunk;
    int eend = min(E, s + chunk);
    for (int e = s + tid; e < eend; e += blockDim.x)
        atomicAdd(&h[edge_row[e] >> BKT_SHIFT], 1);
    __syncthreads();
    for (int i = tid; i < NBKT; i += blockDim.x) {
        int c = h[i];
        if (c) atomicAdd(&bucket_cnt[i], c);
    }
}

// Scan bucket counts -> boff (exclusive), cursorA copy. One 1024-thread block.
__global__ void scan_bkt_kernel(const int* __restrict__ bucket_cnt,
                                int* __restrict__ boff,
                                int* __restrict__ cursorA, int E) {
    __shared__ int sm[1024];
    int tid = threadIdx.x;
    int x = (tid < NBKT) ? bucket_cnt[tid] : 0;
    sm[tid] = x;
    __syncthreads();
    for (int off = 1; off < 1024; off <<= 1) {
        int t = (tid >= off) ? sm[tid - off] : 0;
        __syncthreads();
        sm[tid] += t;
        __syncthreads();
    }
    if (tid < NBKT) {
        int excl = sm[tid] - x;
        boff[tid] = excl;
        cursorA[tid] = excl;
    }
    if (tid == 0) boff[NBKT] = E;
}

// Pass A2: bin edges into bucket segments. Payload packs col(18b)|rowlocal(8b).
__global__ void bin_scatter_kernel(const float* __restrict__ edge_val,
                                   const int*   __restrict__ edge_row,
                                   const int*   __restrict__ edge_col,
                                   int* __restrict__ cursorA,
                                   int2* __restrict__ binned,
                                   int E, int chunk) {
    __shared__ int h[NBKT];
    int tid = threadIdx.x;
    for (int i = tid; i < NBKT; i += blockDim.x) h[i] = 0;
    __syncthreads();
    int s = blockIdx.x * chunk;
    int eend = min(E, s + chunk);
    for (int e = s + tid; e < eend; e += blockDim.x)
        atomicAdd(&h[edge_row[e] >> BKT_SHIFT], 1);
    __syncthreads();
    // block-aggregated reservation: h[i] becomes this block's global base
    for (int i = tid; i < NBKT; i += blockDim.x) {
        int c = h[i];
        if (c) h[i] = atomicAdd(&cursorA[i], c);
    }
    __syncthreads();
    for (int e = s + tid; e < eend; e += blockDim.x) {
        int r = edge_row[e];
        int b = r >> BKT_SHIFT;
        int pos = atomicAdd(&h[b], 1);
        binned[pos] = make_int2(__float_as_int(edge_val[e]),
                                edge_col[e] | ((r & (BKT_W - 1)) << 18));
    }
}

// Pass B: one block per bucket -> exact CSR (row_ptr + sorted (val,col))
__global__ void bucket_to_csr_kernel(const int2* __restrict__ binned,
                                     const int*  __restrict__ boff,
                                     int*  __restrict__ row_ptr,
                                     int2* __restrict__ sorted, int E) {
    int b = blockIdx.x;
    int start = boff[b];
    int end   = boff[b + 1];
    __shared__ int rc[BKT_W];
    __shared__ int sm[BKT_W];
    int tid = threadIdx.x;            // blockDim.x == BKT_W == 256
    rc[tid] = 0;
    __syncthreads();
    for (int e = start + tid; e < end; e += blockDim.x)
        atomicAdd(&rc[(unsigned)binned[e].y >> 18], 1);
    __syncthreads();
    int x = rc[tid];
    sm[tid] = x;
    __syncthreads();
    for (int off = 1; off < BKT_W; off <<= 1) {
        int t = (tid >= off) ? sm[tid - off] : 0;
        __syncthreads();
        sm[tid] += t;
        __syncthreads();
    }
    int excl = sm[tid] - x;
    int gidx = (b << BKT_SHIFT) + tid;
    if (gidx <= NN) row_ptr[gidx] = start + excl;   // bucket 781/tid 64 -> row_ptr[NN]=E
    __syncthreads();
    rc[tid] = excl;
    __syncthreads();
    for (int e = start + tid; e < end; e += blockDim.x) {
        int2 a = binned[e];
        int rl = (unsigned)a.y >> 18;
        int pos = start + atomicAdd(&rc[rl], 1);
        sorted[pos] = make_int2(a.x, a.y & 0x3FFFF);
    }
}

// ---------------------------------------------------------------------------
// Fused CSR SpMM (bf16 gather) + semantic mix. One wave per row;
// lane = (g,p): g = edge slot (4), p = dim quad (16). Lane gathers ushort4
// (4 bf16 dims) of edge e+g's source row. LAST layer writes fp32 (consumed
// only by gamma); earlier layers write bf16 (gather source for next layer).
// No accumulator stream — gamma sums the four layer buffers directly.
// ---------------------------------------------------------------------------
template<bool LAST>
__global__ void spmm_csr_bf16_kernel(const int2* __restrict__ sorted,
                                     const int*  __restrict__ row_ptr,
                                     const unsigned short* __restrict__ src,
                                     const float* __restrict__ symptom_emb,
                                     const float* __restrict__ herb_emb,
                                     const float* __restrict__ user_lw,
                                     const float* __restrict__ item_lw,
                                     int layer,
                                     unsigned short* __restrict__ dst_b,
                                     float* __restrict__ dst_f) {
    int wid  = threadIdx.x >> 6;
    int lane = threadIdx.x & 63;
    int row  = blockIdx.x * (blockDim.x >> 6) + wid;
    if (row >= NN) return;
    int g = lane >> 4;        // edge slot 0..3
    int p = lane & 15;        // dim quad 0..15 (dims 4p..4p+3)

    int start = row_ptr[row];
    int end   = row_ptr[row + 1];

    const ushort4* src4 = (const ushort4*)src;   // row = 16 ushort4

    float4 s0 = {0.f, 0.f, 0.f, 0.f};
    float4 s1 = {0.f, 0.f, 0.f, 0.f};
    int e = start;
    for (; e + 8 <= end; e += 8) {
        int2 a0 = sorted[e + g];
        int2 a1 = sorted[e + 4 + g];
        ushort4 u0 = src4[((size_t)(unsigned)a0.y << 4) + p];
        ushort4 u1 = src4[((size_t)(unsigned)a1.y << 4) + p];
        float v0 = __int_as_float(a0.x);
        float v1 = __int_as_float(a1.x);
        s0.x += v0 * bf2f(u0.x); s0.y += v0 * bf2f(u0.y);
        s0.z += v0 * bf2f(u0.z); s0.w += v0 * bf2f(u0.w);
        s1.x += v1 * bf2f(u1.x); s1.y += v1 * bf2f(u1.y);
        s1.z += v1 * bf2f(u1.z); s1.w += v1 * bf2f(u1.w);
    }
    for (; e < end; e += 4) {
        int idx = e + g;
        int2 a = (idx < end) ? sorted[idx] : make_int2(0, 0);
        ushort4 u = src4[((size_t)(unsigned)a.y << 4) + p];
        float v = __int_as_float(a.x);      // 0.0f for tail slots
        s0.x += v * bf2f(u.x); s0.y += v * bf2f(u.y);
        s0.z += v * bf2f(u.z); s0.w += v * bf2f(u.w);
    }
    float4 s;
    s.x = s0.x + s1.x; s.y = s0.y + s1.y;
    s.z = s0.z + s1.z; s.w = s0.w + s1.w;

    // reduce the 4 edge slots: lanes {p, p+16, p+32, p+48} hold partials
    #pragma unroll
    for (int m = 16; m < 64; m <<= 1) {
        s.x += __shfl_xor(s.x, m, 64);
        s.y += __shfl_xor(s.y, m, 64);
        s.z += __shfl_xor(s.z, m, 64);
        s.w += __shfl_xor(s.w, m, 64);
    }

    if (lane < 16) {   // lanes 0..15 own dim quads of this row
        size_t o = ((size_t)row << 6) + ((size_t)p << 2);
        float wgt;
        float4 sv;
        if (row < U_N) {
            wgt = sigmoidf_(user_lw[layer]);
            sv = *(const float4*)(symptom_emb + o);
        } else {
            wgt = sigmoidf_(item_lw[layer]);
            sv = *(const float4*)(herb_emb + o - ((size_t)U_N << 6));
        }
        float4 r;
        r.x = wgt * s.x + (1.0f - wgt) * sv.x;
        r.y = wgt * s.y + (1.0f - wgt) * sv.y;
        r.z = wgt * s.z + (1.0f - wgt) * sv.z;
        r.w = wgt * s.w + (1.0f - wgt) * sv.w;
        if (LAST) {
            *(float4*)(dst_f + o) = r;
        } else {
            ushort4 rb;
            rb.x = f2bf(r.x); rb.y = f2bf(r.y);
            rb.z = f2bf(r.z); rb.w = f2bf(r.w);
            *(ushort4*)(dst_b + o) = rb;
        }
    }
}

// ---------------------------------------------------------------------------
// Readout: one wave per (user,item) pair.
// acc[row] = e0f + e1b + e2b + e3f summed on the fly; gamma = dot / 16.
// ---------------------------------------------------------------------------
__global__ void gamma_kernel(const float* __restrict__ e0f,
                             const unsigned short* __restrict__ e1b,
                             const unsigned short* __restrict__ e2b,
                             const float* __restrict__ e3f,
                             const int* __restrict__ users,
                             const int* __restrict__ items,
                             float* __restrict__ out,
                             int B) {
    int gtid = blockIdx.x * blockDim.x + threadIdx.x;
    int wid  = gtid >> 6;
    int lane = threadIdx.x & 63;
    if (wid >= B) return;
    int u  = users[wid];
    int it = items[wid];
    size_t ou = ((size_t)u << 6) | lane;
    size_t oi = ((size_t)(U_N + it) << 6) | lane;
    float su = e0f[ou] + bf2f(e1b[ou]) + bf2f(e2b[ou]) + e3f[ou];
    float si = e0f[oi] + bf2f(e1b[oi]) + bf2f(e2b[oi]) + e3f[oi];
    float p = su * si;
    #pragma unroll
    for (int off = 32; off > 0; off >>= 1)
        p += __shfl_down(p, off, 64);
    if (lane == 0) out[wid] = p * (1.0f / 16.0f);
}

// ---------------------------------------------------------------------------
// Fallback (round-1 atomic scatter) kernels, used only if ws too small
// ---------------------------------------------------------------------------
__global__ void fuse0_kernel(const float* __restrict__ user_emb,
                             const float* __restrict__ item_emb,
                             const float* __restrict__ symptom_emb,
                             const float* __restrict__ herb_emb,
                             const float* __restrict__ user_lw,
                             const float* __restrict__ item_lw,
                             float* __restrict__ bufA,
                             float* __restrict__ acc,
                             float* __restrict__ bufB) {
    long long idx = (long long)blockIdx.x * blockDim.x + threadIdx.x;
    if (idx >= ND4) return;
    float a0 = sigmoidf_(user_lw[0]);
    float b0 = sigmoidf_(item_lw[0]);
    float4 e, s;
    float w;
    if (idx < UD4) {
        e = ((const float4*)user_emb)[idx];
        s = ((const float4*)symptom_emb)[idx];
        w = a0;
    } else {
        long long j = idx - UD4;
        e = ((const float4*)item_emb)[j];
        s = ((const float4*)herb_emb)[j];
        w = b0;
    }
    float4 r;
    r.x = w * e.x + (1.0f - w) * s.x;
    r.y = w * e.y + (1.0f - w) * s.y;
    r.z = w * e.z + (1.0f - w) * s.z;
    r.w = w * e.w + (1.0f - w) * s.w;
    ((float4*)bufA)[idx] = r;
    ((float4*)acc)[idx]  = r;
    float4 z; z.x = z.y = z.z = z.w = 0.0f;
    ((float4*)bufB)[idx] = z;
}

__global__ void spmm_scatter_kernel(const float* __restrict__ edge_val,
                                    const int*   __restrict__ edge_row,
                                    const int*   __restrict__ edge_col,
                                    const float* __restrict__ src,
                                    float*       __restrict__ dst,
                                    long long total) {
    long long idx = (long long)blockIdx.x * blockDim.x + threadIdx.x;
    if (idx >= total) return;
    long long e = idx >> 4;
    int       q = (int)(idx & 15);
    int r = edge_row[e];
    int c = edge_col[e];
    float v = edge_val[e];
    float4 x = *(const float4*)(src + (long long)c * D + q * 4);
    float* d = dst + (long long)r * D + q * 4;
    atomicAdd(d + 0, v * x.x);
    atomicAdd(d + 1, v * x.y);
    atomicAdd(d + 2, v * x.z);
    atomicAdd(d + 3, v * x.w);
}

__global__ void fuse_layer_kernel(const float* __restrict__ symptom_emb,
                                  const float* __restrict__ herb_emb,
                                  const float* __restrict__ user_lw,
                                  const float* __restrict__ item_lw,
                                  int layer,
                                  float* __restrict__ bufA,
                                  float* __restrict__ bufB,
                                  float* __restrict__ acc) {
    long long idx = (long long)blockIdx.x * blockDim.x + threadIdx.x;
    if (idx >= ND4) return;
    float a = sigmoidf_(user_lw[layer]);
    float b = sigmoidf_(item_lw[layer]);
    float4 m = ((float4*)bufB)[idx];
    float4 z; z.x = z.y = z.z = z.w = 0.0f;
    ((float4*)bufB)[idx] = z;
    float4 s;
    float w;
    if (idx < UD4) {
        s = ((const float4*)symptom_emb)[idx];
        w = a;
    } else {
        s = ((const float4*)herb_emb)[idx - UD4];
        w = b;
    }
    float4 r;
    r.x = w * m.x + (1.0f - w) * s.x;
    r.y = w * m.y + (1.0f - w) * s.y;
    r.z = w * m.z + (1.0f - w) * s.z;
    r.w = w * m.w + (1.0f - w) * s.w;
    ((float4*)bufA)[idx] = r;
    float4 ac = ((float4*)acc)[idx];
    ac.x += r.x; ac.y += r.y; ac.z += r.z; ac.w += r.w;
    ((float4*)acc)[idx] = ac;
}

__global__ void gamma_acc_kernel(const float* __restrict__ acc,
                                 const int* __restrict__ users,
                                 const int* __restrict__ items,
                                 float* __restrict__ out,
                                 int B) {
    int gtid = blockIdx.x * blockDim.x + threadIdx.x;
    int wid  = gtid >> 6;
    int lane = threadIdx.x & 63;
    if (wid >= B) return;
    int u  = users[wid];
    int it = items[wid];
    float su = acc[(long long)u * D + lane];
    float si = acc[((long long)(U_N + it)) * D + lane];
    float p = su * si;
    #pragma unroll
    for (int off = 32; off > 0; off >>= 1)
        p += __shfl_down(p, off, 64);
    if (lane == 0) out[wid] = p * (1.0f / 16.0f);
}

extern "C" void kernel_launch(void* const* d_in, const int* in_sizes, int n_in,
                              void* d_out, int out_size, void* d_ws, size_t ws_size,
                              hipStream_t stream) {
    const float* user_emb    = (const float*)d_in[0];
    const float* item_emb    = (const float*)d_in[1];
    const float* symptom_emb = (const float*)d_in[2];
    const float* herb_emb    = (const float*)d_in[3];
    const float* user_lw     = (const float*)d_in[4];
    const float* item_lw     = (const float*)d_in[5];
    const float* edge_val    = (const float*)d_in[6];
    const int*   edge_row    = (const int*)d_in[7];
    const int*   edge_col    = (const int*)d_in[8];
    const int*   users       = (const int*)d_in[9];
    const int*   items       = (const int*)d_in[10];
    float* out = (float*)d_out;

    const int E = in_sizes[6];
    const int B = in_sizes[9];
    const int TPB = 256;

    // ---- fast-path workspace layout (256B-aligned carve) ----
    // Aliasing: e2b reuses e0b's slot (e0b dead after spmm layer 1);
    //           e3f reuses binned's slot (binned dead after pass B).
    size_t off = 0;
    auto carve = [&](size_t bytes) -> char* {
        char* p = (char*)d_ws + off;
        off += (bytes + 255) & ~(size_t)255;
        return p;
    };
    float*          e0f     = (float*)carve(NDLL * 4);
    unsigned short* e0b     = (unsigned short*)carve(NDLL * 2);
    unsigned short* e1b     = (unsigned short*)carve(NDLL * 2);
    int2*           binned  = (int2*)carve((size_t)E * 8);
    int2*           sorted  = (int2*)carve((size_t)E * 8);
    int*            row_ptr = (int*)carve((size_t)(NN + 1) * 4);
    int*            bcnt    = (int*)carve((size_t)NBKT * 4);
    int*            boff    = (int*)carve((size_t)(NBKT + 1) * 4);
    int*            cursorA = (int*)carve((size_t)NBKT * 4);
    const size_t fast_bytes = off;
    unsigned short* e2b = e0b;            // alias (e0b dead after spmm1)
    float*          e3f = (float*)binned; // alias (binned dead after pass B)

    if (ws_size >= fast_bytes) {
        // ================= fast path: bucket-sorted CSR + bf16 gather =======
        int fb = (int)((ND4 + TPB - 1) / TPB);
        fuse0_bf16_kernel<<<fb, TPB, 0, stream>>>(user_emb, item_emb, symptom_emb,
                                                  herb_emb, user_lw, item_lw,
                                                  e0b, e0f);

        int chunk = (E + ABLK - 1) / ABLK;
        zero_bcnt_kernel<<<(NBKT + TPB - 1) / TPB, TPB, 0, stream>>>(bcnt);
        bucket_hist_kernel<<<ABLK, TPB, 0, stream>>>(edge_row, bcnt, E, chunk);
        scan_bkt_kernel<<<1, 1024, 0, stream>>>(bcnt, boff, cursorA, E);
        bin_scatter_kernel<<<ABLK, TPB, 0, stream>>>(edge_val, edge_row, edge_col,
                                                     cursorA, binned, E, chunk);
        bucket_to_csr_kernel<<<NBKT, BKT_W, 0, stream>>>(binned, boff, row_ptr,
                                                         sorted, E);

        int sblocks = (NN * 64 + TPB - 1) / TPB;   // 4 rows (waves) per block
        spmm_csr_bf16_kernel<false><<<sblocks, TPB, 0, stream>>>(
            sorted, row_ptr, e0b, symptom_emb, herb_emb,
            user_lw, item_lw, 1, e1b, nullptr);
        spmm_csr_bf16_kernel<false><<<sblocks, TPB, 0, stream>>>(
            sorted, row_ptr, e1b, symptom_emb, herb_emb,
            user_lw, item_lw, 2, e2b, nullptr);
        spmm_csr_bf16_kernel<true><<<sblocks, TPB, 0, stream>>>(
            sorted, row_ptr, e2b, symptom_emb, herb_emb,
            user_lw, item_lw, 3, nullptr, e3f);

        int gblocks = (B * 64 + TPB - 1) / TPB;
        gamma_kernel<<<gblocks, TPB, 0, stream>>>(e0f, e1b, e2b, e3f,
                                                  users, items, out, B);
    } else {
        // ================= fallback: atomic scatter =========================
        float* bufA = (float*)d_ws;
        float* bufB = bufA + NDLL;
        float* acc2 = bufB + NDLL;

        int fb = (int)((ND4 + TPB - 1) / TPB);
        fuse0_kernel<<<fb, TPB, 0, stream>>>(user_emb, item_emb, symptom_emb,
                                             herb_emb, user_lw, item_lw,
                                             bufA, acc2, bufB);
        for (int layer = 1; layer <= NL; ++layer) {
            long long total = (long long)E * 16;
            int blocks = (int)((total + TPB - 1) / TPB);
            spmm_scatter_kernel<<<blocks, TPB, 0, stream>>>(edge_val, edge_row,
                                                            edge_col, bufA, bufB,
                                                            total);
            int fblocks = (int)((ND4 + TPB - 1) / TPB);
            fuse_layer_kernel<<<fblocks, TPB, 0, stream>>>(symptom_emb, herb_emb,
                                                           user_lw, item_lw, layer,
                                                           bufA, bufB, acc2);
        }
        int gblocks = (B * 64 + TPB - 1) / TPB;
        gamma_acc_kernel<<<gblocks, TPB, 0, stream>>>(acc2, users, items, out, B);
    }
}

// Round 6
// 825.009 us; speedup vs baseline: 19.9141x; 1.1109x over previous
//
#include <hip/hip_runtime.h>

// Problem constants (match reference)
constexpr int U_N = 100000;   // users
constexpr int I_N = 100000;   // items
constexpr int D   = 64;       // latent dim
constexpr int NL  = 3;        // layers
constexpr int NN  = U_N + I_N;              // 200000 nodes
constexpr long long NDLL = (long long)NN * D;
constexpr long long ND4  = NDLL / 4;
constexpr long long UD4  = (long long)U_N * D / 4;

// Bucket sort parameters: bucket = row >> 10  (1024 rows per bucket).
// Run length per (block,bucket) = E/(ABLK*NBKT) = 6.4M/(1024*196) ~= 32 edges
// = 256 B -> coalesced burst writes, write amp ~1.4x (vs 3.8x at 8-edge runs).
constexpr int BKT_SHIFT = 10;
constexpr int BKT_W     = 1024;                     // rows per bucket
constexpr int NBKT      = (NN + BKT_W - 1) / BKT_W; // 196
constexpr int ABLK      = 1024;                     // blocks in binning pass

__device__ __forceinline__ float sigmoidf_(float x) {
    return 1.0f / (1.0f + expf(-x));
}

__device__ __forceinline__ float bf2f(unsigned short b) {
    return __uint_as_float((unsigned int)b << 16);
}
__device__ __forceinline__ unsigned short f2bf(float f) {
    unsigned int u = __float_as_uint(f);
    u += 0x7FFFu + ((u >> 16) & 1u);   // round-to-nearest-even
    return (unsigned short)(u >> 16);
}

// ---------------------------------------------------------------------------
// Layer-0 fusion: e0b(bf16) = fused emb (gather source), e0f(fp32) = same
// (read by gamma at full precision).
// ---------------------------------------------------------------------------
__global__ void fuse0_bf16_kernel(const float* __restrict__ user_emb,
                                  const float* __restrict__ item_emb,
                                  const float* __restrict__ symptom_emb,
                                  const float* __restrict__ herb_emb,
                                  const float* __restrict__ user_lw,
                                  const float* __restrict__ item_lw,
                                  unsigned short* __restrict__ e0b,
                                  float* __restrict__ e0f) {
    long long idx = (long long)blockIdx.x * blockDim.x + threadIdx.x;
    if (idx >= ND4) return;
    float a0 = sigmoidf_(user_lw[0]);
    float b0 = sigmoidf_(item_lw[0]);
    float4 e, s;
    float w;
    if (idx < UD4) {
        e = ((const float4*)user_emb)[idx];
        s = ((const float4*)symptom_emb)[idx];
        w = a0;
    } else {
        long long j = idx - UD4;
        e = ((const float4*)item_emb)[j];
        s = ((const float4*)herb_emb)[j];
        w = b0;
    }
    float4 r;
    r.x = w * e.x + (1.0f - w) * s.x;
    r.y = w * e.y + (1.0f - w) * s.y;
    r.z = w * e.z + (1.0f - w) * s.z;
    r.w = w * e.w + (1.0f - w) * s.w;
    ((float4*)e0f)[idx] = r;
    ushort4 rb;
    rb.x = f2bf(r.x); rb.y = f2bf(r.y); rb.z = f2bf(r.z); rb.w = f2bf(r.w);
    ((ushort4*)e0b)[idx] = rb;
}

// ---------------------------------------------------------------------------
// CSR build via 2-level bucket sort (1024 rows per bucket)
// ---------------------------------------------------------------------------
__global__ void zero_bcnt_kernel(int* __restrict__ bucket_cnt) {
    int i = blockIdx.x * blockDim.x + threadIdx.x;
    if (i < NBKT) bucket_cnt[i] = 0;
}

// Pass A1: per-block LDS histogram of bucket ids, merged with global atomics
__global__ void bucket_hist_kernel(const int* __restrict__ edge_row,
                                   int* __restrict__ bucket_cnt,
                                   int E, int chunk) {
    __shared__ int h[NBKT];
    int tid = threadIdx.x;
    for (int i = tid; i < NBKT; i += blockDim.x) h[i] = 0;
    __syncthreads();
    int s = blockIdx.x * chunk;
    int eend = min(E, s + chunk);
    for (int e = s + tid; e < eend; e += blockDim.x)
        atomicAdd(&h[edge_row[e] >> BKT_SHIFT], 1);
    __syncthreads();
    for (int i = tid; i < NBKT; i += blockDim.x) {
        int c = h[i];
        if (c) atomicAdd(&bucket_cnt[i], c);
    }
}

// Scan bucket counts -> boff (exclusive), cursorA copy. One 256-thread block
// (NBKT = 196 <= 256).
__global__ void scan_bkt_kernel(const int* __restrict__ bucket_cnt,
                                int* __restrict__ boff,
                                int* __restrict__ cursorA, int E) {
    __shared__ int sm[256];
    int tid = threadIdx.x;
    int x = (tid < NBKT) ? bucket_cnt[tid] : 0;
    sm[tid] = x;
    __syncthreads();
    for (int off = 1; off < 256; off <<= 1) {
        int t = (tid >= off) ? sm[tid - off] : 0;
        __syncthreads();
        sm[tid] += t;
        __syncthreads();
    }
    if (tid < NBKT) {
        int excl = sm[tid] - x;
        boff[tid] = excl;
        cursorA[tid] = excl;
    }
    if (tid == 0) boff[NBKT] = E;
}

// Pass A2: bin edges into bucket segments. Payload packs rowlocal(10b)<<18|col(18b).
__global__ void bin_scatter_kernel(const float* __restrict__ edge_val,
                                   const int*   __restrict__ edge_row,
                                   const int*   __restrict__ edge_col,
                                   int* __restrict__ cursorA,
                                   int2* __restrict__ binned,
                                   int E, int chunk) {
    __shared__ int h[NBKT];
    int tid = threadIdx.x;
    for (int i = tid; i < NBKT; i += blockDim.x) h[i] = 0;
    __syncthreads();
    int s = blockIdx.x * chunk;
    int eend = min(E, s + chunk);
    for (int e = s + tid; e < eend; e += blockDim.x)
        atomicAdd(&h[edge_row[e] >> BKT_SHIFT], 1);
    __syncthreads();
    // block-aggregated reservation: h[i] becomes this block's global base
    for (int i = tid; i < NBKT; i += blockDim.x) {
        int c = h[i];
        if (c) h[i] = atomicAdd(&cursorA[i], c);
    }
    __syncthreads();
    for (int e = s + tid; e < eend; e += blockDim.x) {
        int r = edge_row[e];
        int b = r >> BKT_SHIFT;
        int pos = atomicAdd(&h[b], 1);
        binned[pos] = make_int2(__float_as_int(edge_val[e]),
                                edge_col[e] | ((r & (BKT_W - 1)) << 18));
    }
}

// Pass B: one 1024-thread block per bucket -> exact CSR (row_ptr + sorted)
__global__ void bucket_to_csr_kernel(const int2* __restrict__ binned,
                                     const int*  __restrict__ boff,
                                     int*  __restrict__ row_ptr,
                                     int2* __restrict__ sorted, int E) {
    int b = blockIdx.x;
    int start = boff[b];
    int end   = boff[b + 1];
    __shared__ int rc[BKT_W];
    __shared__ int sm[BKT_W];
    int tid = threadIdx.x;            // blockDim.x == BKT_W == 1024
    rc[tid] = 0;
    __syncthreads();
    for (int e = start + tid; e < end; e += blockDim.x)
        atomicAdd(&rc[(unsigned)binned[e].y >> 18], 1);
    __syncthreads();
    int x = rc[tid];
    sm[tid] = x;
    __syncthreads();
    for (int off = 1; off < BKT_W; off <<= 1) {
        int t = (tid >= off) ? sm[tid - off] : 0;
        __syncthreads();
        sm[tid] += t;
        __syncthreads();
    }
    int excl = sm[tid] - x;
    int gidx = (b << BKT_SHIFT) + tid;
    if (gidx <= NN) row_ptr[gidx] = start + excl;  // last bucket: tid 320 -> row_ptr[NN]=E
    __syncthreads();
    rc[tid] = excl;
    __syncthreads();
    for (int e = start + tid; e < end; e += blockDim.x) {
        int2 a = binned[e];
        int rl = (unsigned)a.y >> 18;
        int pos = start + atomicAdd(&rc[rl], 1);
        sorted[pos] = make_int2(a.x, a.y & 0x3FFFF);
    }
}

// ---------------------------------------------------------------------------
// Fused CSR SpMM (bf16 gather) + semantic mix. One wave per row;
// lane = (g,p): g = edge slot (4), p = dim quad (16). Lane gathers ushort4
// (4 bf16 dims) of edge e+g's source row. Unrolled 16 edges/iter (4 gathers
// in flight). LAST layer writes fp32 (consumed only by gamma); earlier
// layers write bf16 (gather source for next layer).
// ---------------------------------------------------------------------------
template<bool LAST>
__global__ void spmm_csr_bf16_kernel(const int2* __restrict__ sorted,
                                     const int*  __restrict__ row_ptr,
                                     const unsigned short* __restrict__ src,
                                     const float* __restrict__ symptom_emb,
                                     const float* __restrict__ herb_emb,
                                     const float* __restrict__ user_lw,
                                     const float* __restrict__ item_lw,
                                     int layer,
                                     unsigned short* __restrict__ dst_b,
                                     float* __restrict__ dst_f) {
    int wid  = threadIdx.x >> 6;
    int lane = threadIdx.x & 63;
    int row  = blockIdx.x * (blockDim.x >> 6) + wid;
    if (row >= NN) return;
    int g = lane >> 4;        // edge slot 0..3
    int p = lane & 15;        // dim quad 0..15 (dims 4p..4p+3)

    int start = row_ptr[row];
    int end   = row_ptr[row + 1];

    const ushort4* src4 = (const ushort4*)src;   // row = 16 ushort4

    float4 s0 = {0.f, 0.f, 0.f, 0.f};
    float4 s1 = {0.f, 0.f, 0.f, 0.f};
    float4 s2 = {0.f, 0.f, 0.f, 0.f};
    float4 s3 = {0.f, 0.f, 0.f, 0.f};
    int e = start;
    for (; e + 16 <= end; e += 16) {
        int2 a0 = sorted[e + g];
        int2 a1 = sorted[e + 4 + g];
        int2 a2 = sorted[e + 8 + g];
        int2 a3 = sorted[e + 12 + g];
        ushort4 u0 = src4[((size_t)(unsigned)a0.y << 4) + p];
        ushort4 u1 = src4[((size_t)(unsigned)a1.y << 4) + p];
        ushort4 u2 = src4[((size_t)(unsigned)a2.y << 4) + p];
        ushort4 u3 = src4[((size_t)(unsigned)a3.y << 4) + p];
        float v0 = __int_as_float(a0.x);
        float v1 = __int_as_float(a1.x);
        float v2 = __int_as_float(a2.x);
        float v3 = __int_as_float(a3.x);
        s0.x += v0 * bf2f(u0.x); s0.y += v0 * bf2f(u0.y);
        s0.z += v0 * bf2f(u0.z); s0.w += v0 * bf2f(u0.w);
        s1.x += v1 * bf2f(u1.x); s1.y += v1 * bf2f(u1.y);
        s1.z += v1 * bf2f(u1.z); s1.w += v1 * bf2f(u1.w);
        s2.x += v2 * bf2f(u2.x); s2.y += v2 * bf2f(u2.y);
        s2.z += v2 * bf2f(u2.z); s2.w += v2 * bf2f(u2.w);
        s3.x += v3 * bf2f(u3.x); s3.y += v3 * bf2f(u3.y);
        s3.z += v3 * bf2f(u3.z); s3.w += v3 * bf2f(u3.w);
    }
    for (; e + 8 <= end; e += 8) {
        int2 a0 = sorted[e + g];
        int2 a1 = sorted[e + 4 + g];
        ushort4 u0 = src4[((size_t)(unsigned)a0.y << 4) + p];
        ushort4 u1 = src4[((size_t)(unsigned)a1.y << 4) + p];
        float v0 = __int_as_float(a0.x);
        float v1 = __int_as_float(a1.x);
        s0.x += v0 * bf2f(u0.x); s0.y += v0 * bf2f(u0.y);
        s0.z += v0 * bf2f(u0.z); s0.w += v0 * bf2f(u0.w);
        s1.x += v1 * bf2f(u1.x); s1.y += v1 * bf2f(u1.y);
        s1.z += v1 * bf2f(u1.z); s1.w += v1 * bf2f(u1.w);
    }
    for (; e < end; e += 4) {
        int idx = e + g;
        int2 a = (idx < end) ? sorted[idx] : make_int2(0, 0);
        ushort4 u = src4[((size_t)(unsigned)a.y << 4) + p];
        float v = __int_as_float(a.x);      // 0.0f for tail slots
        s0.x += v * bf2f(u.x); s0.y += v * bf2f(u.y);
        s0.z += v * bf2f(u.z); s0.w += v * bf2f(u.w);
    }
    float4 s;
    s.x = (s0.x + s1.x) + (s2.x + s3.x);
    s.y = (s0.y + s1.y) + (s2.y + s3.y);
    s.z = (s0.z + s1.z) + (s2.z + s3.z);
    s.w = (s0.w + s1.w) + (s2.w + s3.w);

    // reduce the 4 edge slots: lanes {p, p+16, p+32, p+48} hold partials
    #pragma unroll
    for (int m = 16; m < 64; m <<= 1) {
        s.x += __shfl_xor(s.x, m, 64);
        s.y += __shfl_xor(s.y, m, 64);
        s.z += __shfl_xor(s.z, m, 64);
        s.w += __shfl_xor(s.w, m, 64);
    }

    if (lane < 16) {   // lanes 0..15 own dim quads of this row
        size_t o = ((size_t)row << 6) + ((size_t)p << 2);
        float wgt;
        float4 sv;
        if (row < U_N) {
            wgt = sigmoidf_(user_lw[layer]);
            sv = *(const float4*)(symptom_emb + o);
        } else {
            wgt = sigmoidf_(item_lw[layer]);
            sv = *(const float4*)(herb_emb + o - ((size_t)U_N << 6));
        }
        float4 r;
        r.x = wgt * s.x + (1.0f - wgt) * sv.x;
        r.y = wgt * s.y + (1.0f - wgt) * sv.y;
        r.z = wgt * s.z + (1.0f - wgt) * sv.z;
        r.w = wgt * s.w + (1.0f - wgt) * sv.w;
        if (LAST) {
            *(float4*)(dst_f + o) = r;
        } else {
            ushort4 rb;
            rb.x = f2bf(r.x); rb.y = f2bf(r.y);
            rb.z = f2bf(r.z); rb.w = f2bf(r.w);
            *(ushort4*)(dst_b + o) = rb;
        }
    }
}

// ---------------------------------------------------------------------------
// Readout: one wave per (user,item) pair.
// acc[row] = e0f + e1b + e2b + e3f summed on the fly; gamma = dot / 16.
// ---------------------------------------------------------------------------
__global__ void gamma_kernel(const float* __restrict__ e0f,
                             const unsigned short* __restrict__ e1b,
                             const unsigned short* __restrict__ e2b,
                             const float* __restrict__ e3f,
                             const int* __restrict__ users,
                             const int* __restrict__ items,
                             float* __restrict__ out,
                             int B) {
    int gtid = blockIdx.x * blockDim.x + threadIdx.x;
    int wid  = gtid >> 6;
    int lane = threadIdx.x & 63;
    if (wid >= B) return;
    int u  = users[wid];
    int it = items[wid];
    size_t ou = ((size_t)u << 6) | lane;
    size_t oi = ((size_t)(U_N + it) << 6) | lane;
    float su = e0f[ou] + bf2f(e1b[ou]) + bf2f(e2b[ou]) + e3f[ou];
    float si = e0f[oi] + bf2f(e1b[oi]) + bf2f(e2b[oi]) + e3f[oi];
    float p = su * si;
    #pragma unroll
    for (int off = 32; off > 0; off >>= 1)
        p += __shfl_down(p, off, 64);
    if (lane == 0) out[wid] = p * (1.0f / 16.0f);
}

// ---------------------------------------------------------------------------
// Fallback (round-1 atomic scatter) kernels, used only if ws too small
// ---------------------------------------------------------------------------
__global__ void fuse0_kernel(const float* __restrict__ user_emb,
                             const float* __restrict__ item_emb,
                             const float* __restrict__ symptom_emb,
                             const float* __restrict__ herb_emb,
                             const float* __restrict__ user_lw,
                             const float* __restrict__ item_lw,
                             float* __restrict__ bufA,
                             float* __restrict__ acc,
                             float* __restrict__ bufB) {
    long long idx = (long long)blockIdx.x * blockDim.x + threadIdx.x;
    if (idx >= ND4) return;
    float a0 = sigmoidf_(user_lw[0]);
    float b0 = sigmoidf_(item_lw[0]);
    float4 e, s;
    float w;
    if (idx < UD4) {
        e = ((const float4*)user_emb)[idx];
        s = ((const float4*)symptom_emb)[idx];
        w = a0;
    } else {
        long long j = idx - UD4;
        e = ((const float4*)item_emb)[j];
        s = ((const float4*)herb_emb)[j];
        w = b0;
    }
    float4 r;
    r.x = w * e.x + (1.0f - w) * s.x;
    r.y = w * e.y + (1.0f - w) * s.y;
    r.z = w * e.z + (1.0f - w) * s.z;
    r.w = w * e.w + (1.0f - w) * s.w;
    ((float4*)bufA)[idx] = r;
    ((float4*)acc)[idx]  = r;
    float4 z; z.x = z.y = z.z = z.w = 0.0f;
    ((float4*)bufB)[idx] = z;
}

__global__ void spmm_scatter_kernel(const float* __restrict__ edge_val,
                                    const int*   __restrict__ edge_row,
                                    const int*   __restrict__ edge_col,
                                    const float* __restrict__ src,
                                    float*       __restrict__ dst,
                                    long long total) {
    long long idx = (long long)blockIdx.x * blockDim.x + threadIdx.x;
    if (idx >= total) return;
    long long e = idx >> 4;
    int       q = (int)(idx & 15);
    int r = edge_row[e];
    int c = edge_col[e];
    float v = edge_val[e];
    float4 x = *(const float4*)(src + (long long)c * D + q * 4);
    float* d = dst + (long long)r * D + q * 4;
    atomicAdd(d + 0, v * x.x);
    atomicAdd(d + 1, v * x.y);
    atomicAdd(d + 2, v * x.z);
    atomicAdd(d + 3, v * x.w);
}

__global__ void fuse_layer_kernel(const float* __restrict__ symptom_emb,
                                  const float* __restrict__ herb_emb,
                                  const float* __restrict__ user_lw,
                                  const float* __restrict__ item_lw,
                                  int layer,
                                  float* __restrict__ bufA,
                                  float* __restrict__ bufB,
                                  float* __restrict__ acc) {
    long long idx = (long long)blockIdx.x * blockDim.x + threadIdx.x;
    if (idx >= ND4) return;
    float a = sigmoidf_(user_lw[layer]);
    float b = sigmoidf_(item_lw[layer]);
    float4 m = ((float4*)bufB)[idx];
    float4 z; z.x = z.y = z.z = z.w = 0.0f;
    ((float4*)bufB)[idx] = z;
    float4 s;
    float w;
    if (idx < UD4) {
        s = ((const float4*)symptom_emb)[idx];
        w = a;
    } else {
        s = ((const float4*)herb_emb)[idx - UD4];
        w = b;
    }
    float4 r;
    r.x = w * m.x + (1.0f - w) * s.x;
    r.y = w * m.y + (1.0f - w) * s.y;
    r.z = w * m.z + (1.0f - w) * s.z;
    r.w = w * m.w + (1.0f - w) * s.w;
    ((float4*)bufA)[idx] = r;
    float4 ac = ((float4*)acc)[idx];
    ac.x += r.x; ac.y += r.y; ac.z += r.z; ac.w += r.w;
    ((float4*)acc)[idx] = ac;
}

__global__ void gamma_acc_kernel(const float* __restrict__ acc,
                                 const int* __restrict__ users,
                                 const int* __restrict__ items,
                                 float* __restrict__ out,
                                 int B) {
    int gtid = blockIdx.x * blockDim.x + threadIdx.x;
    int wid  = gtid >> 6;
    int lane = threadIdx.x & 63;
    if (wid >= B) return;
    int u  = users[wid];
    int it = items[wid];
    float su = acc[(long long)u * D + lane];
    float si = acc[((long long)(U_N + it)) * D + lane];
    float p = su * si;
    #pragma unroll
    for (int off = 32; off > 0; off >>= 1)
        p += __shfl_down(p, off, 64);
    if (lane == 0) out[wid] = p * (1.0f / 16.0f);
}

extern "C" void kernel_launch(void* const* d_in, const int* in_sizes, int n_in,
                              void* d_out, int out_size, void* d_ws, size_t ws_size,
                              hipStream_t stream) {
    const float* user_emb    = (const float*)d_in[0];
    const float* item_emb    = (const float*)d_in[1];
    const float* symptom_emb = (const float*)d_in[2];
    const float* herb_emb    = (const float*)d_in[3];
    const float* user_lw     = (const float*)d_in[4];
    const float* item_lw     = (const float*)d_in[5];
    const float* edge_val    = (const float*)d_in[6];
    const int*   edge_row    = (const int*)d_in[7];
    const int*   edge_col    = (const int*)d_in[8];
    const int*   users       = (const int*)d_in[9];
    const int*   items       = (const int*)d_in[10];
    float* out = (float*)d_out;

    const int E = in_sizes[6];
    const int B = in_sizes[9];
    const int TPB = 256;

    // ---- fast-path workspace layout (256B-aligned carve) ----
    // Aliasing: e2b reuses e0b's slot (e0b dead after spmm layer 1);
    //           e3f reuses binned's slot (binned dead after pass B).
    size_t off = 0;
    auto carve = [&](size_t bytes) -> char* {
        char* p = (char*)d_ws + off;
        off += (bytes + 255) & ~(size_t)255;
        return p;
    };
    float*          e0f     = (float*)carve(NDLL * 4);
    unsigned short* e0b     = (unsigned short*)carve(NDLL * 2);
    unsigned short* e1b     = (unsigned short*)carve(NDLL * 2);
    int2*           binned  = (int2*)carve((size_t)E * 8);
    int2*           sorted  = (int2*)carve((size_t)E * 8);
    int*            row_ptr = (int*)carve((size_t)(NN + 1) * 4);
    int*            bcnt    = (int*)carve((size_t)NBKT * 4);
    int*            boff    = (int*)carve((size_t)(NBKT + 1) * 4);
    int*            cursorA = (int*)carve((size_t)NBKT * 4);
    const size_t fast_bytes = off;
    unsigned short* e2b = e0b;            // alias (e0b dead after spmm1)
    float*          e3f = (float*)binned; // alias (binned dead after pass B)

    if (ws_size >= fast_bytes) {
        // ================= fast path: bucket-sorted CSR + bf16 gather =======
        int fb = (int)((ND4 + TPB - 1) / TPB);
        fuse0_bf16_kernel<<<fb, TPB, 0, stream>>>(user_emb, item_emb, symptom_emb,
                                                  herb_emb, user_lw, item_lw,
                                                  e0b, e0f);

        int chunk = (E + ABLK - 1) / ABLK;
        zero_bcnt_kernel<<<1, TPB, 0, stream>>>(bcnt);
        bucket_hist_kernel<<<ABLK, TPB, 0, stream>>>(edge_row, bcnt, E, chunk);
        scan_bkt_kernel<<<1, 256, 0, stream>>>(bcnt, boff, cursorA, E);
        bin_scatter_kernel<<<ABLK, TPB, 0, stream>>>(edge_val, edge_row, edge_col,
                                                     cursorA, binned, E, chunk);
        bucket_to_csr_kernel<<<NBKT, BKT_W, 0, stream>>>(binned, boff, row_ptr,
                                                         sorted, E);

        int sblocks = (NN * 64 + TPB - 1) / TPB;   // 4 rows (waves) per block
        spmm_csr_bf16_kernel<false><<<sblocks, TPB, 0, stream>>>(
            sorted, row_ptr, e0b, symptom_emb, herb_emb,
            user_lw, item_lw, 1, e1b, nullptr);
        spmm_csr_bf16_kernel<false><<<sblocks, TPB, 0, stream>>>(
            sorted, row_ptr, e1b, symptom_emb, herb_emb,
            user_lw, item_lw, 2, e2b, nullptr);
        spmm_csr_bf16_kernel<true><<<sblocks, TPB, 0, stream>>>(
            sorted, row_ptr, e2b, symptom_emb, herb_emb,
            user_lw, item_lw, 3, nullptr, e3f);

        int gblocks = (B * 64 + TPB - 1) / TPB;
        gamma_kernel<<<gblocks, TPB, 0, stream>>>(e0f, e1b, e2b, e3f,
                                                  users, items, out, B);
    } else {
        // ================= fallback: atomic scatter =========================
        float* bufA = (float*)d_ws;
        float* bufB = bufA + NDLL;
        float* acc2 = bufB + NDLL;

        int fb = (int)((ND4 + TPB - 1) / TPB);
        fuse0_kernel<<<fb, TPB, 0, stream>>>(user_emb, item_emb, symptom_emb,
                                             herb_emb, user_lw, item_lw,
                                             bufA, acc2, bufB);
        for (int layer = 1; layer <= NL; ++layer) {
            long long total = (long long)E * 16;
            int blocks = (int)((total + TPB - 1) / TPB);
            spmm_scatter_kernel<<<blocks, TPB, 0, stream>>>(edge_val, edge_row,
                                                            edge_col, bufA, bufB,
                                                            total);
            int fblocks = (int)((ND4 + TPB - 1) / TPB);
            fuse_layer_kernel<<<fblocks, TPB, 0, stream>>>(symptom_emb, herb_emb,
                                                           user_lw, item_lw, layer,
                                                           bufA, bufB, acc2);
        }
        int gblocks = (B * 64 + TPB - 1) / TPB;
        gamma_acc_kernel<<<gblocks, TPB, 0, stream>>>(acc2, users, items, out, B);
    }
}

// Round 7
// 692.038 us; speedup vs baseline: 23.7405x; 1.1921x over previous
//
#include <hip/hip_runtime.h>

// Problem constants (match reference)
constexpr int U_N = 100000;   // users
constexpr int I_N = 100000;   // items
constexpr int D   = 64;       // latent dim
constexpr int NL  = 3;        // layers
constexpr int NN  = U_N + I_N;              // 200000 nodes
constexpr long long NDLL = (long long)NN * D;
constexpr long long ND4  = NDLL / 4;
constexpr long long UD4  = (long long)U_N * D / 4;

// Bucket sort parameters: bucket = row >> 10  (1024 rows per bucket).
// Run length per (block,bucket) = E/(ABLK*NBKT) ~= 32 edges = 256 B ->
// coalesced burst writes (R6: fixed the 3.8x write amp seen at 8-edge runs).
constexpr int BKT_SHIFT = 10;
constexpr int BKT_W     = 1024;                     // rows per bucket
constexpr int NBKT      = (NN + BKT_W - 1) / BKT_W; // 196
constexpr int ABLK      = 1024;                     // blocks in binning pass

__device__ __forceinline__ float sigmoidf_(float x) {
    return 1.0f / (1.0f + expf(-x));
}

__device__ __forceinline__ float bf2f(unsigned short b) {
    return __uint_as_float((unsigned int)b << 16);
}
__device__ __forceinline__ float bf_lo(unsigned int u) {   // low bf16 of packed pair
    return __uint_as_float(u << 16);
}
__device__ __forceinline__ float bf_hi(unsigned int u) {   // high bf16 (just an AND)
    return __uint_as_float(u & 0xFFFF0000u);
}
__device__ __forceinline__ unsigned short f2bf(float f) {
    unsigned int u = __float_as_uint(f);
    u += 0x7FFFu + ((u >> 16) & 1u);   // round-to-nearest-even
    return (unsigned short)(u >> 16);
}
__device__ __forceinline__ unsigned int pack2bf(float lo, float hi) {
    return (unsigned int)f2bf(lo) | ((unsigned int)f2bf(hi) << 16);
}

// ---------------------------------------------------------------------------
// Layer-0 fusion: e0b(bf16) = fused emb (gather source for layer 1).
// gamma recomputes e0 in fp32 from the inputs, so no fp32 copy is kept.
// ---------------------------------------------------------------------------
__global__ void fuse0_bf16_kernel(const float* __restrict__ user_emb,
                                  const float* __restrict__ item_emb,
                                  const float* __restrict__ symptom_emb,
                                  const float* __restrict__ herb_emb,
                                  const float* __restrict__ user_lw,
                                  const float* __restrict__ item_lw,
                                  unsigned short* __restrict__ e0b) {
    long long idx = (long long)blockIdx.x * blockDim.x + threadIdx.x;
    if (idx >= ND4) return;
    float a0 = sigmoidf_(user_lw[0]);
    float b0 = sigmoidf_(item_lw[0]);
    float4 e, s;
    float w;
    if (idx < UD4) {
        e = ((const float4*)user_emb)[idx];
        s = ((const float4*)symptom_emb)[idx];
        w = a0;
    } else {
        long long j = idx - UD4;
        e = ((const float4*)item_emb)[j];
        s = ((const float4*)herb_emb)[j];
        w = b0;
    }
    ushort4 rb;
    rb.x = f2bf(w * e.x + (1.0f - w) * s.x);
    rb.y = f2bf(w * e.y + (1.0f - w) * s.y);
    rb.z = f2bf(w * e.z + (1.0f - w) * s.z);
    rb.w = f2bf(w * e.w + (1.0f - w) * s.w);
    ((ushort4*)e0b)[idx] = rb;
}

// ---------------------------------------------------------------------------
// CSR build via 2-level bucket sort (1024 rows per bucket)
// ---------------------------------------------------------------------------
__global__ void zero_bcnt_kernel(int* __restrict__ bucket_cnt) {
    int i = blockIdx.x * blockDim.x + threadIdx.x;
    if (i < NBKT) bucket_cnt[i] = 0;
}

__global__ void bucket_hist_kernel(const int* __restrict__ edge_row,
                                   int* __restrict__ bucket_cnt,
                                   int E, int chunk) {
    __shared__ int h[NBKT];
    int tid = threadIdx.x;
    for (int i = tid; i < NBKT; i += blockDim.x) h[i] = 0;
    __syncthreads();
    int s = blockIdx.x * chunk;
    int eend = min(E, s + chunk);
    for (int e = s + tid; e < eend; e += blockDim.x)
        atomicAdd(&h[edge_row[e] >> BKT_SHIFT], 1);
    __syncthreads();
    for (int i = tid; i < NBKT; i += blockDim.x) {
        int c = h[i];
        if (c) atomicAdd(&bucket_cnt[i], c);
    }
}

// Scan bucket counts -> boff (exclusive), cursorA copy. One 256-thread block.
__global__ void scan_bkt_kernel(const int* __restrict__ bucket_cnt,
                                int* __restrict__ boff,
                                int* __restrict__ cursorA, int E) {
    __shared__ int sm[256];
    int tid = threadIdx.x;
    int x = (tid < NBKT) ? bucket_cnt[tid] : 0;
    sm[tid] = x;
    __syncthreads();
    for (int off = 1; off < 256; off <<= 1) {
        int t = (tid >= off) ? sm[tid - off] : 0;
        __syncthreads();
        sm[tid] += t;
        __syncthreads();
    }
    if (tid < NBKT) {
        int excl = sm[tid] - x;
        boff[tid] = excl;
        cursorA[tid] = excl;
    }
    if (tid == 0) boff[NBKT] = E;
}

// Pass A2: bin edges into bucket segments. Payload packs rowlocal(10b)<<18|col(18b).
__global__ void bin_scatter_kernel(const float* __restrict__ edge_val,
                                   const int*   __restrict__ edge_row,
                                   const int*   __restrict__ edge_col,
                                   int* __restrict__ cursorA,
                                   int2* __restrict__ binned,
                                   int E, int chunk) {
    __shared__ int h[NBKT];
    int tid = threadIdx.x;
    for (int i = tid; i < NBKT; i += blockDim.x) h[i] = 0;
    __syncthreads();
    int s = blockIdx.x * chunk;
    int eend = min(E, s + chunk);
    for (int e = s + tid; e < eend; e += blockDim.x)
        atomicAdd(&h[edge_row[e] >> BKT_SHIFT], 1);
    __syncthreads();
    for (int i = tid; i < NBKT; i += blockDim.x) {
        int c = h[i];
        if (c) h[i] = atomicAdd(&cursorA[i], c);
    }
    __syncthreads();
    for (int e = s + tid; e < eend; e += blockDim.x) {
        int r = edge_row[e];
        int b = r >> BKT_SHIFT;
        int pos = atomicAdd(&h[b], 1);
        binned[pos] = make_int2(__float_as_int(edge_val[e]),
                                edge_col[e] | ((r & (BKT_W - 1)) << 18));
    }
}

// Pass B: one 1024-thread block per bucket -> exact CSR (row_ptr + sorted)
__global__ void bucket_to_csr_kernel(const int2* __restrict__ binned,
                                     const int*  __restrict__ boff,
                                     int*  __restrict__ row_ptr,
                                     int2* __restrict__ sorted, int E) {
    int b = blockIdx.x;
    int start = boff[b];
    int end   = boff[b + 1];
    __shared__ int rc[BKT_W];
    __shared__ int sm[BKT_W];
    int tid = threadIdx.x;            // blockDim.x == BKT_W == 1024
    rc[tid] = 0;
    __syncthreads();
    for (int e = start + tid; e < end; e += blockDim.x)
        atomicAdd(&rc[(unsigned)binned[e].y >> 18], 1);
    __syncthreads();
    int x = rc[tid];
    sm[tid] = x;
    __syncthreads();
    for (int off = 1; off < BKT_W; off <<= 1) {
        int t = (tid >= off) ? sm[tid - off] : 0;
        __syncthreads();
        sm[tid] += t;
        __syncthreads();
    }
    int excl = sm[tid] - x;
    int gidx = (b << BKT_SHIFT) + tid;
    if (gidx <= NN) row_ptr[gidx] = start + excl;
    __syncthreads();
    rc[tid] = excl;
    __syncthreads();
    for (int e = start + tid; e < end; e += blockDim.x) {
        int2 a = binned[e];
        int rl = (unsigned)a.y >> 18;
        int pos = start + atomicAdd(&rc[rl], 1);
        sorted[pos] = make_int2(a.x, a.y & 0x3FFFF);
    }
}

// ---------------------------------------------------------------------------
// Core CSR row accumulation: one wave per row; lane = (g,p):
// g = edge slot (8), p = dim oct (8). Lane gathers uint4 (8 bf16 dims) of
// edge e+g's source row: one dwordx4 moves 1 KiB/wave and covers 8 edges.
// Returns this lane's 8 partial dims reduced across the 8 edge slots.
// ---------------------------------------------------------------------------
__device__ __forceinline__ void csr_row_sum(const int2* __restrict__ sorted,
                                            const uint4* __restrict__ src16,
                                            int start, int end,
                                            int g, int p, float s[8]) {
    float s0[8], s1[8];
    #pragma unroll
    for (int j = 0; j < 8; ++j) { s0[j] = 0.f; s1[j] = 0.f; }
    int e = start;
    for (; e + 16 <= end; e += 16) {
        int2 a0 = sorted[e + g];
        int2 a1 = sorted[e + 8 + g];
        uint4 q0 = src16[((size_t)(unsigned)a0.y << 3) + p];
        uint4 q1 = src16[((size_t)(unsigned)a1.y << 3) + p];
        float v0 = __int_as_float(a0.x);
        float v1 = __int_as_float(a1.x);
        s0[0] += v0 * bf_lo(q0.x); s0[1] += v0 * bf_hi(q0.x);
        s0[2] += v0 * bf_lo(q0.y); s0[3] += v0 * bf_hi(q0.y);
        s0[4] += v0 * bf_lo(q0.z); s0[5] += v0 * bf_hi(q0.z);
        s0[6] += v0 * bf_lo(q0.w); s0[7] += v0 * bf_hi(q0.w);
        s1[0] += v1 * bf_lo(q1.x); s1[1] += v1 * bf_hi(q1.x);
        s1[2] += v1 * bf_lo(q1.y); s1[3] += v1 * bf_hi(q1.y);
        s1[4] += v1 * bf_lo(q1.z); s1[5] += v1 * bf_hi(q1.z);
        s1[6] += v1 * bf_lo(q1.w); s1[7] += v1 * bf_hi(q1.w);
    }
    for (; e < end; e += 8) {
        int idx = e + g;
        int2 a = (idx < end) ? sorted[idx] : make_int2(0, 0);
        uint4 q = src16[((size_t)(unsigned)a.y << 3) + p];
        float v = __int_as_float(a.x);      // 0.0f for tail slots
        s0[0] += v * bf_lo(q.x); s0[1] += v * bf_hi(q.x);
        s0[2] += v * bf_lo(q.y); s0[3] += v * bf_hi(q.y);
        s0[4] += v * bf_lo(q.z); s0[5] += v * bf_hi(q.z);
        s0[6] += v * bf_lo(q.w); s0[7] += v * bf_hi(q.w);
    }
    #pragma unroll
    for (int j = 0; j < 8; ++j) s[j] = s0[j] + s1[j];
    // reduce the 8 edge slots: lanes with same p hold partials
    #pragma unroll
    for (int m = 8; m < 64; m <<= 1) {
        #pragma unroll
        for (int j = 0; j < 8; ++j)
            s[j] += __shfl_xor(s[j], m, 64);
    }
}

// Full SpMM over all N rows: dst_b(bf16) = w*A@src + (1-w)*sem
__global__ void spmm_csr_full_kernel(const int2* __restrict__ sorted,
                                     const int*  __restrict__ row_ptr,
                                     const unsigned short* __restrict__ src,
                                     const float* __restrict__ symptom_emb,
                                     const float* __restrict__ herb_emb,
                                     const float* __restrict__ user_lw,
                                     const float* __restrict__ item_lw,
                                     int layer,
                                     unsigned short* __restrict__ dst_b) {
    int wid  = threadIdx.x >> 6;
    int lane = threadIdx.x & 63;
    int row  = blockIdx.x * (blockDim.x >> 6) + wid;
    if (row >= NN) return;
    int g = lane >> 3;        // edge slot 0..7
    int p = lane & 7;         // dim oct 0..7 (dims 8p..8p+7)

    float s[8];
    csr_row_sum(sorted, (const uint4*)src, row_ptr[row], row_ptr[row + 1],
                g, p, s);

    if (lane < 8) {   // lanes 0..7 own dim octs of this row
        size_t o = ((size_t)row << 6) + ((size_t)p << 3);
        float wgt;
        const float* semp;
        if (row < U_N) {
            wgt = sigmoidf_(user_lw[layer]);
            semp = symptom_emb + o;
        } else {
            wgt = sigmoidf_(item_lw[layer]);
            semp = herb_emb + o - ((size_t)U_N << 6);
        }
        float4 sa = *(const float4*)semp;
        float4 sb = *(const float4*)(semp + 4);
        float r0 = wgt * s[0] + (1.0f - wgt) * sa.x;
        float r1 = wgt * s[1] + (1.0f - wgt) * sa.y;
        float r2 = wgt * s[2] + (1.0f - wgt) * sa.z;
        float r3 = wgt * s[3] + (1.0f - wgt) * sa.w;
        float r4 = wgt * s[4] + (1.0f - wgt) * sb.x;
        float r5 = wgt * s[5] + (1.0f - wgt) * sb.y;
        float r6 = wgt * s[6] + (1.0f - wgt) * sb.z;
        float r7 = wgt * s[7] + (1.0f - wgt) * sb.w;
        uint4 ob;
        ob.x = pack2bf(r0, r1);
        ob.y = pack2bf(r2, r3);
        ob.z = pack2bf(r4, r5);
        ob.w = pack2bf(r6, r7);
        *(uint4*)(dst_b + o) = ob;
    }
}

// Compact last-layer SpMM: only the 2B rows gamma needs (users then items),
// output fp32 indexed by pair position (duplicates recomputed — harmless).
__global__ void spmm_csr_compact_kernel(const int2* __restrict__ sorted,
                                        const int*  __restrict__ row_ptr,
                                        const unsigned short* __restrict__ src,
                                        const float* __restrict__ symptom_emb,
                                        const float* __restrict__ herb_emb,
                                        const float* __restrict__ user_lw,
                                        const float* __restrict__ item_lw,
                                        int layer,
                                        const int* __restrict__ users,
                                        const int* __restrict__ items,
                                        float* __restrict__ e3c,
                                        int B) {
    int wid  = threadIdx.x >> 6;
    int lane = threadIdx.x & 63;
    int b    = blockIdx.x * (blockDim.x >> 6) + wid;
    if (b >= 2 * B) return;
    int row = (b < B) ? users[b] : (items[b - B] + U_N);
    int g = lane >> 3;
    int p = lane & 7;

    float s[8];
    csr_row_sum(sorted, (const uint4*)src, row_ptr[row], row_ptr[row + 1],
                g, p, s);

    if (lane < 8) {
        size_t orow = ((size_t)row << 6) + ((size_t)p << 3);
        float wgt;
        const float* semp;
        if (row < U_N) {
            wgt = sigmoidf_(user_lw[layer]);
            semp = symptom_emb + orow;
        } else {
            wgt = sigmoidf_(item_lw[layer]);
            semp = herb_emb + orow - ((size_t)U_N << 6);
        }
        float4 sa = *(const float4*)semp;
        float4 sb = *(const float4*)(semp + 4);
        float4 ra, rb;
        ra.x = wgt * s[0] + (1.0f - wgt) * sa.x;
        ra.y = wgt * s[1] + (1.0f - wgt) * sa.y;
        ra.z = wgt * s[2] + (1.0f - wgt) * sa.z;
        ra.w = wgt * s[3] + (1.0f - wgt) * sa.w;
        rb.x = wgt * s[4] + (1.0f - wgt) * sb.x;
        rb.y = wgt * s[5] + (1.0f - wgt) * sb.y;
        rb.z = wgt * s[6] + (1.0f - wgt) * sb.z;
        rb.w = wgt * s[7] + (1.0f - wgt) * sb.w;
        float* op = e3c + ((size_t)b << 6) + ((size_t)p << 3);
        *(float4*)op = ra;
        *(float4*)(op + 4) = rb;
    }
}

// ---------------------------------------------------------------------------
// Readout: one wave per (user,item) pair.
// su = e0(recomputed fp32) + e1b + e2b + e3c; gamma = dot(su,si) / 16.
// ---------------------------------------------------------------------------
__global__ void gamma_kernel(const float* __restrict__ user_emb,
                             const float* __restrict__ item_emb,
                             const float* __restrict__ symptom_emb,
                             const float* __restrict__ herb_emb,
                             const float* __restrict__ user_lw,
                             const float* __restrict__ item_lw,
                             const unsigned short* __restrict__ e1b,
                             const unsigned short* __restrict__ e2b,
                             const float* __restrict__ e3c,
                             const int* __restrict__ users,
                             const int* __restrict__ items,
                             float* __restrict__ out,
                             int B) {
    int gtid = blockIdx.x * blockDim.x + threadIdx.x;
    int wid  = gtid >> 6;
    int lane = threadIdx.x & 63;
    if (wid >= B) return;
    float a0 = sigmoidf_(user_lw[0]);
    float b0 = sigmoidf_(item_lw[0]);
    int u  = users[wid];
    int it = items[wid];
    size_t ou = ((size_t)u << 6) | lane;
    size_t oi = ((size_t)(U_N + it) << 6) | lane;
    size_t oi_loc = ((size_t)it << 6) | lane;
    float e0u = a0 * user_emb[ou] + (1.0f - a0) * symptom_emb[ou];
    float e0i = b0 * item_emb[oi_loc] + (1.0f - b0) * herb_emb[oi_loc];
    float su = e0u + bf2f(e1b[ou]) + bf2f(e2b[ou])
             + e3c[((size_t)wid << 6) | lane];
    float si = e0i + bf2f(e1b[oi]) + bf2f(e2b[oi])
             + e3c[((size_t)(B + wid) << 6) | lane];
    float pr = su * si;
    #pragma unroll
    for (int off = 32; off > 0; off >>= 1)
        pr += __shfl_down(pr, off, 64);
    if (lane == 0) out[wid] = pr * (1.0f / 16.0f);
}

// ---------------------------------------------------------------------------
// Fallback (round-1 atomic scatter) kernels, used only if ws too small
// ---------------------------------------------------------------------------
__global__ void fuse0_kernel(const float* __restrict__ user_emb,
                             const float* __restrict__ item_emb,
                             const float* __restrict__ symptom_emb,
                             const float* __restrict__ herb_emb,
                             const float* __restrict__ user_lw,
                             const float* __restrict__ item_lw,
                             float* __restrict__ bufA,
                             float* __restrict__ acc,
                             float* __restrict__ bufB) {
    long long idx = (long long)blockIdx.x * blockDim.x + threadIdx.x;
    if (idx >= ND4) return;
    float a0 = sigmoidf_(user_lw[0]);
    float b0 = sigmoidf_(item_lw[0]);
    float4 e, s;
    float w;
    if (idx < UD4) {
        e = ((const float4*)user_emb)[idx];
        s = ((const float4*)symptom_emb)[idx];
        w = a0;
    } else {
        long long j = idx - UD4;
        e = ((const float4*)item_emb)[j];
        s = ((const float4*)herb_emb)[j];
        w = b0;
    }
    float4 r;
    r.x = w * e.x + (1.0f - w) * s.x;
    r.y = w * e.y + (1.0f - w) * s.y;
    r.z = w * e.z + (1.0f - w) * s.z;
    r.w = w * e.w + (1.0f - w) * s.w;
    ((float4*)bufA)[idx] = r;
    ((float4*)acc)[idx]  = r;
    float4 z; z.x = z.y = z.z = z.w = 0.0f;
    ((float4*)bufB)[idx] = z;
}

__global__ void spmm_scatter_kernel(const float* __restrict__ edge_val,
                                    const int*   __restrict__ edge_row,
                                    const int*   __restrict__ edge_col,
                                    const float* __restrict__ src,
                                    float*       __restrict__ dst,
                                    long long total) {
    long long idx = (long long)blockIdx.x * blockDim.x + threadIdx.x;
    if (idx >= total) return;
    long long e = idx >> 4;
    int       q = (int)(idx & 15);
    int r = edge_row[e];
    int c = edge_col[e];
    float v = edge_val[e];
    float4 x = *(const float4*)(src + (long long)c * D + q * 4);
    float* d = dst + (long long)r * D + q * 4;
    atomicAdd(d + 0, v * x.x);
    atomicAdd(d + 1, v * x.y);
    atomicAdd(d + 2, v * x.z);
    atomicAdd(d + 3, v * x.w);
}

__global__ void fuse_layer_kernel(const float* __restrict__ symptom_emb,
                                  const float* __restrict__ herb_emb,
                                  const float* __restrict__ user_lw,
                                  const float* __restrict__ item_lw,
                                  int layer,
                                  float* __restrict__ bufA,
                                  float* __restrict__ bufB,
                                  float* __restrict__ acc) {
    long long idx = (long long)blockIdx.x * blockDim.x + threadIdx.x;
    if (idx >= ND4) return;
    float a = sigmoidf_(user_lw[layer]);
    float b = sigmoidf_(item_lw[layer]);
    float4 m = ((float4*)bufB)[idx];
    float4 z; z.x = z.y = z.z = z.w = 0.0f;
    ((float4*)bufB)[idx] = z;
    float4 s;
    float w;
    if (idx < UD4) {
        s = ((const float4*)symptom_emb)[idx];
        w = a;
    } else {
        s = ((const float4*)herb_emb)[idx - UD4];
        w = b;
    }
    float4 r;
    r.x = w * m.x + (1.0f - w) * s.x;
    r.y = w * m.y + (1.0f - w) * s.y;
    r.z = w * m.z + (1.0f - w) * s.z;
    r.w = w * m.w + (1.0f - w) * s.w;
    ((float4*)bufA)[idx] = r;
    float4 ac = ((float4*)acc)[idx];
    ac.x += r.x; ac.y += r.y; ac.z += r.z; ac.w += r.w;
    ((float4*)acc)[idx] = ac;
}

__global__ void gamma_acc_kernel(const float* __restrict__ acc,
                                 const int* __restrict__ users,
                                 const int* __restrict__ items,
                                 float* __restrict__ out,
                                 int B) {
    int gtid = blockIdx.x * blockDim.x + threadIdx.x;
    int wid  = gtid >> 6;
    int lane = threadIdx.x & 63;
    if (wid >= B) return;
    int u  = users[wid];
    int it = items[wid];
    float su = acc[(long long)u * D + lane];
    float si = acc[((long long)(U_N + it)) * D + lane];
    float p = su * si;
    #pragma unroll
    for (int off = 32; off > 0; off >>= 1)
        p += __shfl_down(p, off, 64);
    if (lane == 0) out[wid] = p * (1.0f / 16.0f);
}

extern "C" void kernel_launch(void* const* d_in, const int* in_sizes, int n_in,
                              void* d_out, int out_size, void* d_ws, size_t ws_size,
                              hipStream_t stream) {
    const float* user_emb    = (const float*)d_in[0];
    const float* item_emb    = (const float*)d_in[1];
    const float* symptom_emb = (const float*)d_in[2];
    const float* herb_emb    = (const float*)d_in[3];
    const float* user_lw     = (const float*)d_in[4];
    const float* item_lw     = (const float*)d_in[5];
    const float* edge_val    = (const float*)d_in[6];
    const int*   edge_row    = (const int*)d_in[7];
    const int*   edge_col    = (const int*)d_in[8];
    const int*   users       = (const int*)d_in[9];
    const int*   items       = (const int*)d_in[10];
    float* out = (float*)d_out;

    const int E = in_sizes[6];
    const int B = in_sizes[9];
    const int TPB = 256;

    // ---- fast-path workspace layout (256B-aligned carve) ----
    // Aliasing: e2b reuses e0b's slot (e0b dead after spmm layer 1);
    //           e3c reuses binned's slot (binned dead after pass B).
    size_t off = 0;
    auto carve = [&](size_t bytes) -> char* {
        char* p = (char*)d_ws + off;
        off += (bytes + 255) & ~(size_t)255;
        return p;
    };
    unsigned short* e0b     = (unsigned short*)carve(NDLL * 2);
    unsigned short* e1b     = (unsigned short*)carve(NDLL * 2);
    int2*           binned  = (int2*)carve((size_t)E * 8);
    int2*           sorted  = (int2*)carve((size_t)E * 8);
    int*            row_ptr = (int*)carve((size_t)(NN + 1) * 4);
    int*            bcnt    = (int*)carve((size_t)NBKT * 4);
    int*            boff    = (int*)carve((size_t)(NBKT + 1) * 4);
    int*            cursorA = (int*)carve((size_t)NBKT * 4);
    const size_t fast_bytes = off;
    unsigned short* e2b = e0b;            // alias (e0b dead after spmm1)
    float*          e3c = (float*)binned; // alias (binned dead after pass B);
                                          // needs 2B*64*4 = 8.4 MB <= E*8

    if (ws_size >= fast_bytes && (size_t)E * 8 >= (size_t)2 * B * D * 4) {
        // ================= fast path: bucket-sorted CSR + bf16 gather =======
        int fb = (int)((ND4 + TPB - 1) / TPB);
        fuse0_bf16_kernel<<<fb, TPB, 0, stream>>>(user_emb, item_emb, symptom_emb,
                                                  herb_emb, user_lw, item_lw, e0b);

        int chunk = (E + ABLK - 1) / ABLK;
        zero_bcnt_kernel<<<1, TPB, 0, stream>>>(bcnt);
        bucket_hist_kernel<<<ABLK, TPB, 0, stream>>>(edge_row, bcnt, E, chunk);
        scan_bkt_kernel<<<1, 256, 0, stream>>>(bcnt, boff, cursorA, E);
        bin_scatter_kernel<<<ABLK, TPB, 0, stream>>>(edge_val, edge_row, edge_col,
                                                     cursorA, binned, E, chunk);
        bucket_to_csr_kernel<<<NBKT, BKT_W, 0, stream>>>(binned, boff, row_ptr,
                                                         sorted, E);

        int sblocks = (NN * 64 + TPB - 1) / TPB;   // 4 rows (waves) per block
        spmm_csr_full_kernel<<<sblocks, TPB, 0, stream>>>(
            sorted, row_ptr, e0b, symptom_emb, herb_emb,
            user_lw, item_lw, 1, e1b);
        spmm_csr_full_kernel<<<sblocks, TPB, 0, stream>>>(
            sorted, row_ptr, e1b, symptom_emb, herb_emb,
            user_lw, item_lw, 2, e2b);
        int cblocks = (2 * B * 64 + TPB - 1) / TPB;
        spmm_csr_compact_kernel<<<cblocks, TPB, 0, stream>>>(
            sorted, row_ptr, e2b, symptom_emb, herb_emb,
            user_lw, item_lw, 3, users, items, e3c, B);

        int gblocks = (B * 64 + TPB - 1) / TPB;
        gamma_kernel<<<gblocks, TPB, 0, stream>>>(user_emb, item_emb,
                                                  symptom_emb, herb_emb,
                                                  user_lw, item_lw,
                                                  e1b, e2b, e3c,
                                                  users, items, out, B);
    } else {
        // ================= fallback: atomic scatter =========================
        float* bufA = (float*)d_ws;
        float* bufB = bufA + NDLL;
        float* acc2 = bufB + NDLL;

        int fb = (int)((ND4 + TPB - 1) / TPB);
        fuse0_kernel<<<fb, TPB, 0, stream>>>(user_emb, item_emb, symptom_emb,
                                             herb_emb, user_lw, item_lw,
                                             bufA, acc2, bufB);
        for (int layer = 1; layer <= NL; ++layer) {
            long long total = (long long)E * 16;
            int blocks = (int)((total + TPB - 1) / TPB);
            spmm_scatter_kernel<<<blocks, TPB, 0, stream>>>(edge_val, edge_row,
                                                            edge_col, bufA, bufB,
                                                            total);
            int fblocks = (int)((ND4 + TPB - 1) / TPB);
            fuse_layer_kernel<<<fblocks, TPB, 0, stream>>>(symptom_emb, herb_emb,
                                                           user_lw, item_lw, layer,
                                                           bufA, bufB, acc2);
        }
        int gblocks = (B * 64 + TPB - 1) / TPB;
        gamma_acc_kernel<<<gblocks, TPB, 0, stream>>>(acc2, users, items, out, B);
    }
}

// Round 8
// 690.025 us; speedup vs baseline: 23.8098x; 1.0029x over previous
//
#include <hip/hip_runtime.h>

// Problem constants (match reference)
constexpr int U_N = 100000;   // users
constexpr int I_N = 100000;   // items
constexpr int D   = 64;       // latent dim
constexpr int NL  = 3;        // layers
constexpr int NN  = U_N + I_N;              // 200000 nodes
constexpr long long NDLL = (long long)NN * D;
constexpr long long ND4  = NDLL / 4;
constexpr long long UD4  = (long long)U_N * D / 4;

// Bucket sort parameters: bucket = row >> 10  (1024 rows per bucket).
// Run length per (block,bucket) = E/(ABLK*NBKT) ~= 32 edges = 256 B ->
// coalesced burst writes (R6: fixed the 3.8x write amp seen at 8-edge runs).
constexpr int BKT_SHIFT = 10;
constexpr int BKT_W     = 1024;                     // rows per bucket
constexpr int NBKT      = (NN + BKT_W - 1) / BKT_W; // 196
constexpr int ABLK      = 1024;                     // blocks in binning pass

typedef float f32x2 __attribute__((ext_vector_type(2)));

__device__ __forceinline__ float sigmoidf_(float x) {
    return 1.0f / (1.0f + expf(-x));
}

__device__ __forceinline__ float bf2f(unsigned short b) {
    return __uint_as_float((unsigned int)b << 16);
}
__device__ __forceinline__ float bf_lo(unsigned int u) {
    return __uint_as_float(u << 16);
}
__device__ __forceinline__ float bf_hi(unsigned int u) {
    return __uint_as_float(u & 0xFFFF0000u);
}
// unpack a packed bf16 pair into a float2 (dims 2k, 2k+1)
__device__ __forceinline__ f32x2 bfpair(unsigned int u) {
    f32x2 r;
    r.x = __uint_as_float(u << 16);
    r.y = __uint_as_float(u & 0xFFFF0000u);
    return r;
}
__device__ __forceinline__ unsigned short f2bf(float f) {
    unsigned int u = __float_as_uint(f);
    u += 0x7FFFu + ((u >> 16) & 1u);   // round-to-nearest-even
    return (unsigned short)(u >> 16);
}
__device__ __forceinline__ unsigned int pack2bf(float lo, float hi) {
    return (unsigned int)f2bf(lo) | ((unsigned int)f2bf(hi) << 16);
}

// ---------------------------------------------------------------------------
// Layer-0 fusion: e0b(bf16) = fused emb (gather source for layer 1).
// Downstream consumers recompute e0 in fp32 from the inputs.
// ---------------------------------------------------------------------------
__global__ void fuse0_bf16_kernel(const float* __restrict__ user_emb,
                                  const float* __restrict__ item_emb,
                                  const float* __restrict__ symptom_emb,
                                  const float* __restrict__ herb_emb,
                                  const float* __restrict__ user_lw,
                                  const float* __restrict__ item_lw,
                                  unsigned short* __restrict__ e0b) {
    long long idx = (long long)blockIdx.x * blockDim.x + threadIdx.x;
    if (idx >= ND4) return;
    float a0 = sigmoidf_(user_lw[0]);
    float b0 = sigmoidf_(item_lw[0]);
    float4 e, s;
    float w;
    if (idx < UD4) {
        e = ((const float4*)user_emb)[idx];
        s = ((const float4*)symptom_emb)[idx];
        w = a0;
    } else {
        long long j = idx - UD4;
        e = ((const float4*)item_emb)[j];
        s = ((const float4*)herb_emb)[j];
        w = b0;
    }
    ushort4 rb;
    rb.x = f2bf(w * e.x + (1.0f - w) * s.x);
    rb.y = f2bf(w * e.y + (1.0f - w) * s.y);
    rb.z = f2bf(w * e.z + (1.0f - w) * s.z);
    rb.w = f2bf(w * e.w + (1.0f - w) * s.w);
    ((ushort4*)e0b)[idx] = rb;
}

// ---------------------------------------------------------------------------
// CSR build via 2-level bucket sort (1024 rows per bucket)
// ---------------------------------------------------------------------------
__global__ void zero_bcnt_kernel(int* __restrict__ bucket_cnt) {
    int i = blockIdx.x * blockDim.x + threadIdx.x;
    if (i < NBKT) bucket_cnt[i] = 0;
}

__global__ void bucket_hist_kernel(const int* __restrict__ edge_row,
                                   int* __restrict__ bucket_cnt,
                                   int E, int chunk) {
    __shared__ int h[NBKT];
    int tid = threadIdx.x;
    for (int i = tid; i < NBKT; i += blockDim.x) h[i] = 0;
    __syncthreads();
    int s = blockIdx.x * chunk;
    int eend = min(E, s + chunk);
    for (int e = s + tid; e < eend; e += blockDim.x)
        atomicAdd(&h[edge_row[e] >> BKT_SHIFT], 1);
    __syncthreads();
    for (int i = tid; i < NBKT; i += blockDim.x) {
        int c = h[i];
        if (c) atomicAdd(&bucket_cnt[i], c);
    }
}

// Scan bucket counts -> boff (exclusive), cursorA copy. One 256-thread block.
__global__ void scan_bkt_kernel(const int* __restrict__ bucket_cnt,
                                int* __restrict__ boff,
                                int* __restrict__ cursorA, int E) {
    __shared__ int sm[256];
    int tid = threadIdx.x;
    int x = (tid < NBKT) ? bucket_cnt[tid] : 0;
    sm[tid] = x;
    __syncthreads();
    for (int off = 1; off < 256; off <<= 1) {
        int t = (tid >= off) ? sm[tid - off] : 0;
        __syncthreads();
        sm[tid] += t;
        __syncthreads();
    }
    if (tid < NBKT) {
        int excl = sm[tid] - x;
        boff[tid] = excl;
        cursorA[tid] = excl;
    }
    if (tid == 0) boff[NBKT] = E;
}

// Pass A2: bin edges into bucket segments. Payload packs rowlocal(10b)<<18|col(18b).
__global__ void bin_scatter_kernel(const float* __restrict__ edge_val,
                                   const int*   __restrict__ edge_row,
                                   const int*   __restrict__ edge_col,
                                   int* __restrict__ cursorA,
                                   int2* __restrict__ binned,
                                   int E, int chunk) {
    __shared__ int h[NBKT];
    int tid = threadIdx.x;
    for (int i = tid; i < NBKT; i += blockDim.x) h[i] = 0;
    __syncthreads();
    int s = blockIdx.x * chunk;
    int eend = min(E, s + chunk);
    for (int e = s + tid; e < eend; e += blockDim.x)
        atomicAdd(&h[edge_row[e] >> BKT_SHIFT], 1);
    __syncthreads();
    for (int i = tid; i < NBKT; i += blockDim.x) {
        int c = h[i];
        if (c) h[i] = atomicAdd(&cursorA[i], c);
    }
    __syncthreads();
    for (int e = s + tid; e < eend; e += blockDim.x) {
        int r = edge_row[e];
        int b = r >> BKT_SHIFT;
        int pos = atomicAdd(&h[b], 1);
        binned[pos] = make_int2(__float_as_int(edge_val[e]),
                                edge_col[e] | ((r & (BKT_W - 1)) << 18));
    }
}

// Pass B: one 1024-thread block per bucket -> exact CSR (row_ptr + sorted)
__global__ void bucket_to_csr_kernel(const int2* __restrict__ binned,
                                     const int*  __restrict__ boff,
                                     int*  __restrict__ row_ptr,
                                     int2* __restrict__ sorted, int E) {
    int b = blockIdx.x;
    int start = boff[b];
    int end   = boff[b + 1];
    __shared__ int rc[BKT_W];
    __shared__ int sm[BKT_W];
    int tid = threadIdx.x;            // blockDim.x == BKT_W == 1024
    rc[tid] = 0;
    __syncthreads();
    for (int e = start + tid; e < end; e += blockDim.x)
        atomicAdd(&rc[(unsigned)binned[e].y >> 18], 1);
    __syncthreads();
    int x = rc[tid];
    sm[tid] = x;
    __syncthreads();
    for (int off = 1; off < BKT_W; off <<= 1) {
        int t = (tid >= off) ? sm[tid - off] : 0;
        __syncthreads();
        sm[tid] += t;
        __syncthreads();
    }
    int excl = sm[tid] - x;
    int gidx = (b << BKT_SHIFT) + tid;
    if (gidx <= NN) row_ptr[gidx] = start + excl;
    __syncthreads();
    rc[tid] = excl;
    __syncthreads();
    for (int e = start + tid; e < end; e += blockDim.x) {
        int2 a = binned[e];
        int rl = (unsigned)a.y >> 18;
        int pos = start + atomicAdd(&rc[rl], 1);
        sorted[pos] = make_int2(a.x, a.y & 0x3FFFF);
    }
}

// ---------------------------------------------------------------------------
// Core CSR row accumulation: one wave per row; lane = (g,p):
// g = edge slot (8), p = dim oct (8). Lane gathers uint4 (8 bf16 dims) of
// edge e+g's source row. Accumulation uses float2 ext-vectors so the backend
// can select v_pk_fma_f32 (2 fp32/lane/issue on CDNA4).
// Output: s[4] float2 = this lane's 8 dims, reduced across the 8 edge slots.
// ---------------------------------------------------------------------------
__device__ __forceinline__ void csr_row_sum(const int2* __restrict__ sorted,
                                            const uint4* __restrict__ src16,
                                            int start, int end,
                                            int g, int p, f32x2 s[4]) {
    f32x2 s0[4], s1[4];
    #pragma unroll
    for (int j = 0; j < 4; ++j) {
        s0[j] = (f32x2){0.f, 0.f};
        s1[j] = (f32x2){0.f, 0.f};
    }
    int e = start;
    for (; e + 16 <= end; e += 16) {
        int2 a0 = sorted[e + g];
        int2 a1 = sorted[e + 8 + g];
        uint4 q0 = src16[((size_t)(unsigned)a0.y << 3) + p];
        uint4 q1 = src16[((size_t)(unsigned)a1.y << 3) + p];
        f32x2 v0; v0.x = __int_as_float(a0.x); v0.y = v0.x;
        f32x2 v1; v1.x = __int_as_float(a1.x); v1.y = v1.x;
        s0[0] += v0 * bfpair(q0.x);
        s0[1] += v0 * bfpair(q0.y);
        s0[2] += v0 * bfpair(q0.z);
        s0[3] += v0 * bfpair(q0.w);
        s1[0] += v1 * bfpair(q1.x);
        s1[1] += v1 * bfpair(q1.y);
        s1[2] += v1 * bfpair(q1.z);
        s1[3] += v1 * bfpair(q1.w);
    }
    for (; e < end; e += 8) {
        int idx = e + g;
        int2 a = (idx < end) ? sorted[idx] : make_int2(0, 0);
        uint4 q = src16[((size_t)(unsigned)a.y << 3) + p];
        f32x2 v; v.x = __int_as_float(a.x); v.y = v.x;   // 0 for tail slots
        s0[0] += v * bfpair(q.x);
        s0[1] += v * bfpair(q.y);
        s0[2] += v * bfpair(q.z);
        s0[3] += v * bfpair(q.w);
    }
    #pragma unroll
    for (int j = 0; j < 4; ++j) s[j] = s0[j] + s1[j];
    // reduce the 8 edge slots: lanes with same p hold partials
    #pragma unroll
    for (int m = 8; m < 64; m <<= 1) {
        #pragma unroll
        for (int j = 0; j < 4; ++j) {
            f32x2 t;
            t.x = __shfl_xor(s[j].x, m, 64);
            t.y = __shfl_xor(s[j].y, m, 64);
            s[j] += t;
        }
    }
}

// Full SpMM over all N rows: dst_b(bf16) = w*A@src + (1-w)*sem
__global__ void spmm_csr_full_kernel(const int2* __restrict__ sorted,
                                     const int*  __restrict__ row_ptr,
                                     const unsigned short* __restrict__ src,
                                     const float* __restrict__ symptom_emb,
                                     const float* __restrict__ herb_emb,
                                     const float* __restrict__ user_lw,
                                     const float* __restrict__ item_lw,
                                     int layer,
                                     unsigned short* __restrict__ dst_b) {
    int wid  = threadIdx.x >> 6;
    int lane = threadIdx.x & 63;
    int row  = blockIdx.x * (blockDim.x >> 6) + wid;
    if (row >= NN) return;
    int g = lane >> 3;        // edge slot 0..7
    int p = lane & 7;         // dim oct 0..7 (dims 8p..8p+7)

    f32x2 s[4];
    csr_row_sum(sorted, (const uint4*)src, row_ptr[row], row_ptr[row + 1],
                g, p, s);

    if (lane < 8) {   // lanes 0..7 own dim octs of this row
        size_t o = ((size_t)row << 6) + ((size_t)p << 3);
        float wgt;
        const float* semp;
        if (row < U_N) {
            wgt = sigmoidf_(user_lw[layer]);
            semp = symptom_emb + o;
        } else {
            wgt = sigmoidf_(item_lw[layer]);
            semp = herb_emb + o - ((size_t)U_N << 6);
        }
        float4 sa = *(const float4*)semp;
        float4 sb = *(const float4*)(semp + 4);
        float r0 = wgt * s[0].x + (1.0f - wgt) * sa.x;
        float r1 = wgt * s[0].y + (1.0f - wgt) * sa.y;
        float r2 = wgt * s[1].x + (1.0f - wgt) * sa.z;
        float r3 = wgt * s[1].y + (1.0f - wgt) * sa.w;
        float r4 = wgt * s[2].x + (1.0f - wgt) * sb.x;
        float r5 = wgt * s[2].y + (1.0f - wgt) * sb.y;
        float r6 = wgt * s[3].x + (1.0f - wgt) * sb.z;
        float r7 = wgt * s[3].y + (1.0f - wgt) * sb.w;
        uint4 ob;
        ob.x = pack2bf(r0, r1);
        ob.y = pack2bf(r2, r3);
        ob.z = pack2bf(r4, r5);
        ob.w = pack2bf(r6, r7);
        *(uint4*)(dst_b + o) = ob;
    }
}

// Compact last-layer SpMM over the 2B pair rows, FUSED with the accumulator
// sum: writes su[pair_slot] = e0(recomputed fp32) + e1b + e2b + e3 to e3c.
// gamma then just dots e3c[b] with e3c[B+b].
__global__ void spmm_csr_compact_kernel(const int2* __restrict__ sorted,
                                        const int*  __restrict__ row_ptr,
                                        const unsigned short* __restrict__ src,
                                        const float* __restrict__ user_emb,
                                        const float* __restrict__ item_emb,
                                        const float* __restrict__ symptom_emb,
                                        const float* __restrict__ herb_emb,
                                        const float* __restrict__ user_lw,
                                        const float* __restrict__ item_lw,
                                        int layer,
                                        const int* __restrict__ users,
                                        const int* __restrict__ items,
                                        const unsigned short* __restrict__ e1b,
                                        const unsigned short* __restrict__ e2b,
                                        float* __restrict__ e3c,
                                        int B) {
    int wid  = threadIdx.x >> 6;
    int lane = threadIdx.x & 63;
    int b    = blockIdx.x * (blockDim.x >> 6) + wid;
    if (b >= 2 * B) return;
    int row = (b < B) ? users[b] : (items[b - B] + U_N);
    int g = lane >> 3;
    int p = lane & 7;

    f32x2 s[4];
    csr_row_sum(sorted, (const uint4*)src, row_ptr[row], row_ptr[row + 1],
                g, p, s);

    if (lane < 8) {
        size_t orow = ((size_t)row << 6) + ((size_t)p << 3);
        float wgt, w0;
        const float* semp;
        const float* embp;
        if (row < U_N) {
            wgt = sigmoidf_(user_lw[layer]);
            w0  = sigmoidf_(user_lw[0]);
            semp = symptom_emb + orow;
            embp = user_emb + orow;
        } else {
            size_t ol = orow - ((size_t)U_N << 6);
            wgt = sigmoidf_(item_lw[layer]);
            w0  = sigmoidf_(item_lw[0]);
            semp = herb_emb + ol;
            embp = item_emb + ol;
        }
        float4 sa = *(const float4*)semp;
        float4 sb = *(const float4*)(semp + 4);
        float4 ea = *(const float4*)embp;
        float4 eb = *(const float4*)(embp + 4);
        uint4 q1 = ((const uint4*)e1b)[((size_t)row << 3) + p];
        uint4 q2 = ((const uint4*)e2b)[((size_t)row << 3) + p];
        // su_j = e0_j + e1_j + e2_j + e3_j
        float4 ra, rb;
        ra.x = (w0 * ea.x + (1.0f - w0) * sa.x) + bf_lo(q1.x) + bf_lo(q2.x)
             + (wgt * s[0].x + (1.0f - wgt) * sa.x);
        ra.y = (w0 * ea.y + (1.0f - w0) * sa.y) + bf_hi(q1.x) + bf_hi(q2.x)
             + (wgt * s[0].y + (1.0f - wgt) * sa.y);
        ra.z = (w0 * ea.z + (1.0f - w0) * sa.z) + bf_lo(q1.y) + bf_lo(q2.y)
             + (wgt * s[1].x + (1.0f - wgt) * sa.z);
        ra.w = (w0 * ea.w + (1.0f - w0) * sa.w) + bf_hi(q1.y) + bf_hi(q2.y)
             + (wgt * s[1].y + (1.0f - wgt) * sa.w);
        rb.x = (w0 * eb.x + (1.0f - w0) * sb.x) + bf_lo(q1.z) + bf_lo(q2.z)
             + (wgt * s[2].x + (1.0f - wgt) * sb.x);
        rb.y = (w0 * eb.y + (1.0f - w0) * sb.y) + bf_hi(q1.z) + bf_hi(q2.z)
             + (wgt * s[2].y + (1.0f - wgt) * sb.y);
        rb.z = (w0 * eb.z + (1.0f - w0) * sb.z) + bf_lo(q1.w) + bf_lo(q2.w)
             + (wgt * s[3].x + (1.0f - wgt) * sb.z);
        rb.w = (w0 * eb.w + (1.0f - w0) * sb.w) + bf_hi(q1.w) + bf_hi(q2.w)
             + (wgt * s[3].y + (1.0f - wgt) * sb.w);
        float* op = e3c + ((size_t)b << 6) + ((size_t)p << 3);
        *(float4*)op = ra;
        *(float4*)(op + 4) = rb;
    }
}

// ---------------------------------------------------------------------------
// Readout: one wave per (user,item) pair; gamma = dot(su, si) / 16 where
// su/si are the pre-summed accumulator rows in e3c.
// ---------------------------------------------------------------------------
__global__ void gamma_kernel(const float* __restrict__ e3c,
                             float* __restrict__ out,
                             int B) {
    int gtid = blockIdx.x * blockDim.x + threadIdx.x;
    int wid  = gtid >> 6;
    int lane = threadIdx.x & 63;
    if (wid >= B) return;
    float su = e3c[((size_t)wid << 6) | lane];
    float si = e3c[((size_t)(B + wid) << 6) | lane];
    float pr = su * si;
    #pragma unroll
    for (int off = 32; off > 0; off >>= 1)
        pr += __shfl_down(pr, off, 64);
    if (lane == 0) out[wid] = pr * (1.0f / 16.0f);
}

// ---------------------------------------------------------------------------
// Fallback (round-1 atomic scatter) kernels, used only if ws too small
// ---------------------------------------------------------------------------
__global__ void fuse0_kernel(const float* __restrict__ user_emb,
                             const float* __restrict__ item_emb,
                             const float* __restrict__ symptom_emb,
                             const float* __restrict__ herb_emb,
                             const float* __restrict__ user_lw,
                             const float* __restrict__ item_lw,
                             float* __restrict__ bufA,
                             float* __restrict__ acc,
                             float* __restrict__ bufB) {
    long long idx = (long long)blockIdx.x * blockDim.x + threadIdx.x;
    if (idx >= ND4) return;
    float a0 = sigmoidf_(user_lw[0]);
    float b0 = sigmoidf_(item_lw[0]);
    float4 e, s;
    float w;
    if (idx < UD4) {
        e = ((const float4*)user_emb)[idx];
        s = ((const float4*)symptom_emb)[idx];
        w = a0;
    } else {
        long long j = idx - UD4;
        e = ((const float4*)item_emb)[j];
        s = ((const float4*)herb_emb)[j];
        w = b0;
    }
    float4 r;
    r.x = w * e.x + (1.0f - w) * s.x;
    r.y = w * e.y + (1.0f - w) * s.y;
    r.z = w * e.z + (1.0f - w) * s.z;
    r.w = w * e.w + (1.0f - w) * s.w;
    ((float4*)bufA)[idx] = r;
    ((float4*)acc)[idx]  = r;
    float4 z; z.x = z.y = z.z = z.w = 0.0f;
    ((float4*)bufB)[idx] = z;
}

__global__ void spmm_scatter_kernel(const float* __restrict__ edge_val,
                                    const int*   __restrict__ edge_row,
                                    const int*   __restrict__ edge_col,
                                    const float* __restrict__ src,
                                    float*       __restrict__ dst,
                                    long long total) {
    long long idx = (long long)blockIdx.x * blockDim.x + threadIdx.x;
    if (idx >= total) return;
    long long e = idx >> 4;
    int       q = (int)(idx & 15);
    int r = edge_row[e];
    int c = edge_col[e];
    float v = edge_val[e];
    float4 x = *(const float4*)(src + (long long)c * D + q * 4);
    float* d = dst + (long long)r * D + q * 4;
    atomicAdd(d + 0, v * x.x);
    atomicAdd(d + 1, v * x.y);
    atomicAdd(d + 2, v * x.z);
    atomicAdd(d + 3, v * x.w);
}

__global__ void fuse_layer_kernel(const float* __restrict__ symptom_emb,
                                  const float* __restrict__ herb_emb,
                                  const float* __restrict__ user_lw,
                                  const float* __restrict__ item_lw,
                                  int layer,
                                  float* __restrict__ bufA,
                                  float* __restrict__ bufB,
                                  float* __restrict__ acc) {
    long long idx = (long long)blockIdx.x * blockDim.x + threadIdx.x;
    if (idx >= ND4) return;
    float a = sigmoidf_(user_lw[layer]);
    float b = sigmoidf_(item_lw[layer]);
    float4 m = ((float4*)bufB)[idx];
    float4 z; z.x = z.y = z.z = z.w = 0.0f;
    ((float4*)bufB)[idx] = z;
    float4 s;
    float w;
    if (idx < UD4) {
        s = ((const float4*)symptom_emb)[idx];
        w = a;
    } else {
        s = ((const float4*)herb_emb)[idx - UD4];
        w = b;
    }
    float4 r;
    r.x = w * m.x + (1.0f - w) * s.x;
    r.y = w * m.y + (1.0f - w) * s.y;
    r.z = w * m.z + (1.0f - w) * s.z;
    r.w = w * m.w + (1.0f - w) * s.w;
    ((float4*)bufA)[idx] = r;
    float4 ac = ((float4*)acc)[idx];
    ac.x += r.x; ac.y += r.y; ac.z += r.z; ac.w += r.w;
    ((float4*)acc)[idx] = ac;
}

__global__ void gamma_acc_kernel(const float* __restrict__ acc,
                                 const int* __restrict__ users,
                                 const int* __restrict__ items,
                                 float* __restrict__ out,
                                 int B) {
    int gtid = blockIdx.x * blockDim.x + threadIdx.x;
    int wid  = gtid >> 6;
    int lane = threadIdx.x & 63;
    if (wid >= B) return;
    int u  = users[wid];
    int it = items[wid];
    float su = acc[(long long)u * D + lane];
    float si = acc[((long long)(U_N + it)) * D + lane];
    float p = su * si;
    #pragma unroll
    for (int off = 32; off > 0; off >>= 1)
        p += __shfl_down(p, off, 64);
    if (lane == 0) out[wid] = p * (1.0f / 16.0f);
}

extern "C" void kernel_launch(void* const* d_in, const int* in_sizes, int n_in,
                              void* d_out, int out_size, void* d_ws, size_t ws_size,
                              hipStream_t stream) {
    const float* user_emb    = (const float*)d_in[0];
    const float* item_emb    = (const float*)d_in[1];
    const float* symptom_emb = (const float*)d_in[2];
    const float* herb_emb    = (const float*)d_in[3];
    const float* user_lw     = (const float*)d_in[4];
    const float* item_lw     = (const float*)d_in[5];
    const float* edge_val    = (const float*)d_in[6];
    const int*   edge_row    = (const int*)d_in[7];
    const int*   edge_col    = (const int*)d_in[8];
    const int*   users       = (const int*)d_in[9];
    const int*   items       = (const int*)d_in[10];
    float* out = (float*)d_out;

    const int E = in_sizes[6];
    const int B = in_sizes[9];
    const int TPB = 256;

    // ---- fast-path workspace layout (256B-aligned carve) ----
    // Aliasing: e2b reuses e0b's slot (e0b dead after spmm layer 1);
    //           e3c reuses binned's slot (binned dead after pass B).
    size_t off = 0;
    auto carve = [&](size_t bytes) -> char* {
        char* p = (char*)d_ws + off;
        off += (bytes + 255) & ~(size_t)255;
        return p;
    };
    unsigned short* e0b     = (unsigned short*)carve(NDLL * 2);
    unsigned short* e1b     = (unsigned short*)carve(NDLL * 2);
    int2*           binned  = (int2*)carve((size_t)E * 8);
    int2*           sorted  = (int2*)carve((size_t)E * 8);
    int*            row_ptr = (int*)carve((size_t)(NN + 1) * 4);
    int*            bcnt    = (int*)carve((size_t)NBKT * 4);
    int*            boff    = (int*)carve((size_t)(NBKT + 1) * 4);
    int*            cursorA = (int*)carve((size_t)NBKT * 4);
    const size_t fast_bytes = off;
    unsigned short* e2b = e0b;            // alias (e0b dead after spmm1)
    float*          e3c = (float*)binned; // alias (binned dead after pass B);
                                          // needs 2B*64*4 = 8.4 MB <= E*8

    if (ws_size >= fast_bytes && (size_t)E * 8 >= (size_t)2 * B * D * 4) {
        // ================= fast path: bucket-sorted CSR + bf16 gather =======
        int fb = (int)((ND4 + TPB - 1) / TPB);
        fuse0_bf16_kernel<<<fb, TPB, 0, stream>>>(user_emb, item_emb, symptom_emb,
                                                  herb_emb, user_lw, item_lw, e0b);

        int chunk = (E + ABLK - 1) / ABLK;
        zero_bcnt_kernel<<<1, TPB, 0, stream>>>(bcnt);
        bucket_hist_kernel<<<ABLK, TPB, 0, stream>>>(edge_row, bcnt, E, chunk);
        scan_bkt_kernel<<<1, 256, 0, stream>>>(bcnt, boff, cursorA, E);
        bin_scatter_kernel<<<ABLK, TPB, 0, stream>>>(edge_val, edge_row, edge_col,
                                                     cursorA, binned, E, chunk);
        bucket_to_csr_kernel<<<NBKT, BKT_W, 0, stream>>>(binned, boff, row_ptr,
                                                         sorted, E);

        int sblocks = (NN * 64 + TPB - 1) / TPB;   // 4 rows (waves) per block
        spmm_csr_full_kernel<<<sblocks, TPB, 0, stream>>>(
            sorted, row_ptr, e0b, symptom_emb, herb_emb,
            user_lw, item_lw, 1, e1b);
        spmm_csr_full_kernel<<<sblocks, TPB, 0, stream>>>(
            sorted, row_ptr, e1b, symptom_emb, herb_emb,
            user_lw, item_lw, 2, e2b);
        int cblocks = (2 * B * 64 + TPB - 1) / TPB;
        spmm_csr_compact_kernel<<<cblocks, TPB, 0, stream>>>(
            sorted, row_ptr, e2b, user_emb, item_emb, symptom_emb, herb_emb,
            user_lw, item_lw, 3, users, items, e1b, e2b, e3c, B);

        int gblocks = (B * 64 + TPB - 1) / TPB;
        gamma_kernel<<<gblocks, TPB, 0, stream>>>(e3c, out, B);
    } else {
        // ================= fallback: atomic scatter =========================
        float* bufA = (float*)d_ws;
        float* bufB = bufA + NDLL;
        float* acc2 = bufB + NDLL;

        int fb = (int)((ND4 + TPB - 1) / TPB);
        fuse0_kernel<<<fb, TPB, 0, stream>>>(user_emb, item_emb, symptom_emb,
                                             herb_emb, user_lw, item_lw,
                                             bufA, acc2, bufB);
        for (int layer = 1; layer <= NL; ++layer) {
            long long total = (long long)E * 16;
            int blocks = (int)((total + TPB - 1) / TPB);
            spmm_scatter_kernel<<<blocks, TPB, 0, stream>>>(edge_val, edge_row,
                                                            edge_col, bufA, bufB,
                                                            total);
            int fblocks = (int)((ND4 + TPB - 1) / TPB);
            fuse_layer_kernel<<<fblocks, TPB, 0, stream>>>(symptom_emb, herb_emb,
                                                           user_lw, item_lw, layer,
                                                           bufA, bufB, acc2);
        }
        int gblocks = (B * 64 + TPB - 1) / TPB;
        gamma_acc_kernel<<<gblocks, TPB, 0, stream>>>(acc2, users, items, out, B);
    }
}